// Round 7
// baseline (332.136 us; speedup 1.0000x reference)
//
#include <hip/hip_runtime.h>
#include <stdint.h>
#include <math.h>

typedef __bf16 bf16;
typedef __bf16 bf16x4 __attribute__((ext_vector_type(4)));
typedef __bf16 bf16x8 __attribute__((ext_vector_type(8)));
typedef float  f32x4  __attribute__((ext_vector_type(4)));
typedef float  f32x16 __attribute__((ext_vector_type(16)));

#define B_DIM 8192
#define K_DIM 4096
#define N_DIM 4096
#define MEM_H 1048576
#define HMOD  1047552   // MEM_H - 32*32
#define NT    (K_DIM / 64)

// ---------------- host-side numpy legacy RNG replication ----------------
static void mt_randint3(uint32_t seed, long long R[3]) {
  uint32_t mt[624];
  mt[0] = seed;
  for (int i = 1; i < 624; i++)
    mt[i] = 1812433253u * (mt[i - 1] ^ (mt[i - 1] >> 30)) + (uint32_t)i;
  int pos = 624;
  auto next32 = [&]() -> uint32_t {
    if (pos >= 624) {
      for (int i = 0; i < 624; i++) {
        uint32_t y = (mt[i] & 0x80000000u) | (mt[(i + 1) % 624] & 0x7fffffffu);
        uint32_t v = mt[(i + 397) % 624] ^ (y >> 1);
        if (y & 1u) v ^= 0x9908b0dfu;
        mt[i] = v;
      }
      pos = 0;
    }
    uint32_t y = mt[pos++];
    y ^= y >> 11;
    y ^= (y << 7) & 0x9d2c5680u;
    y ^= (y << 15) & 0xefc60000u;
    y ^= y >> 18;
    return y;
  };
  for (int j = 0; j < 3; j++) {
    uint32_t v;
    do { v = next32() & 0x7fffffffu; } while (v > 0x7ffffffdu);
    R[j] = 1LL + (long long)v;
  }
}

// ------------- fused pre-pass: convert x AND build W^T -------------------
__global__ void k_prep(const float* __restrict__ x, bf16* __restrict__ xb,
                       const float* __restrict__ hw, bf16* __restrict__ wt,
                       long long R1, long long R2, long long R3) {
  if (blockIdx.x < 16384) {
    int i = blockIdx.x * 256 + threadIdx.x;
    const f32x4* p = (const f32x4*)x;
    f32x4 a = p[2 * i], b = p[2 * i + 1];
    bf16x8 o;
    o[0] = (bf16)a[0]; o[1] = (bf16)a[1]; o[2] = (bf16)a[2]; o[3] = (bf16)a[3];
    o[4] = (bf16)b[0]; o[5] = (bf16)b[1]; o[6] = (bf16)b[2]; o[7] = (bf16)b[3];
    ((bf16x8*)xb)[i] = o;
  } else {
    int tile = blockIdx.x - 16384;
    int kb = tile & 127, nb = tile >> 7;
    long long v = (long long)kb * R3 + (long long)nb * R2 + R1;
    int start = (int)((v % 2147483647LL) % (long long)HMOD);
    const float* src = hw + start;
    int t  = threadIdx.x;
    int nl = t >> 3;
    int k4 = t & 7;
    bf16x4 o;
#pragma unroll
    for (int j = 0; j < 4; j++) o[j] = (bf16)src[(k4 * 4 + j) * 32 + nl];
    *(bf16x4*)(wt + (size_t)(nb * 32 + nl) * K_DIM + kb * 32 + k4 * 4) = o;
  }
}

// ---------------- 256x256x64 GEMM, 8 waves, 32x32x16 MFMA ----------------
// Skeleton identical to the verified R4 kernel (staging units, swizzle,
// vmcnt(6)-before-barrier schedule). Only the MFMA shape changed:
// 32x32x16 runs at 2495 TF ubench vs 2075 for 16x16x32.
// A-frag: row = lane&31, k = (lane>>5)*8 + j  (mirror of verified 16x16 map)
// C/D:    col = lane&31, row = (reg&3) + 8*(reg>>2) + 4*(lane>>5)
__device__ __forceinline__ void gload_lds16(const void* g, void* l) {
  __builtin_amdgcn_global_load_lds(
      (const __attribute__((address_space(1))) void*)g,
      (__attribute__((address_space(3))) void*)l, 16, 0, 0);
}

#define ASM_VMCNT(n) asm volatile("s_waitcnt vmcnt(" #n ")" ::: "memory")
#define BAR() asm volatile("s_barrier" ::: "memory")

// one cluster: row-block pair rsel (0: rb0-1, 1: rb2-3) x col-block cb,
// all 4 k-slices. 8 MFMAs, 2 independent acc chains.
#define MM32(rsel, cb) do {                                                    \
  __builtin_amdgcn_s_setprio(1);                                               \
  _Pragma("unroll")                                                            \
  for (int ks = 0; ks < 4; ks++)                                               \
    _Pragma("unroll")                                                          \
    for (int rb2 = 0; rb2 < 2; rb2++)                                          \
      acc[(rsel)*2 + rb2][(cb)] =                                              \
          __builtin_amdgcn_mfma_f32_32x32x16_bf16(                             \
              af[rb2][ks], bg[(cb)][ks], acc[(rsel)*2 + rb2][(cb)], 0, 0, 0);  \
  __builtin_amdgcn_s_setprio(0);                                               \
} while (0)

__global__ __launch_bounds__(512, 2) void k_gemm(const bf16* __restrict__ A,
                                                 const bf16* __restrict__ Bt,
                                                 float* __restrict__ partial) {
  // [buf][op 0=A 1=B][half][128*64] : 128 KiB
  __shared__ bf16 sm[2][2][2][128 * 64];
  int bid = blockIdx.x;
  int swz = (bid & 7) * 64 + (bid >> 3);     // 512 blocks, 8 XCDs, bijective
  int mt = swz & 31, nt = swz >> 5;
  int tid = threadIdx.x;
  int w = tid >> 6, lane = tid & 63;
  int wm = w >> 2, wn = w & 3;               // 2 x 4 wave grid, 128x64 each
  int l31 = lane & 31, hi = lane >> 5;
  int r8 = lane >> 3, gg = lane & 7;
  int swcol = ((gg ^ r8) << 3);              // pre-swizzled source col (elems)
  size_t bm = (size_t)mt * 256, bn = (size_t)nt * 256;
  const bf16* Ab = A + bm * K_DIM;
  const bf16* Bb = Bt + bn * K_DIM;

  f32x16 acc[4][2] = {};                     // [row-block 32][col-block 32]
  bf16x8 af[2][4], bg[2][4];                 // [block][k-slice of 16]

  // stage one 64-row unit; each wave stages rows w*8..w*8+7 (VERBATIM R4)
  auto STAGE_AU = [&](int q, int tt, int buf) {
    gload_lds16(Ab + (size_t)(q * 64 + w * 8 + r8) * K_DIM + tt * 64 + swcol,
                &sm[buf][0][q >> 1][(q & 1) * 4096 + w * 8 * 64]);
  };
  auto STAGE_BV = [&](int j, int tt, int buf) {
    gload_lds16(Bb + (size_t)(j * 64 + w * 8 + r8) * K_DIM + tt * 64 + swcol,
                &sm[buf][1][j >> 1][(j & 1) * 4096 + w * 8 * 64]);
  };
  // swizzled fragment reads for 32x32x16: granule = ks*2 + hi
  auto RDA = [&](int buf, int rblk, int ks) -> bf16x8 {
    const bf16* h = &sm[buf][0][wm][0];
    int row = rblk * 32 + l31;
    int gc = ks * 2 + hi;
    return *(const bf16x8*)(h + row * 64 + ((gc ^ (row & 7)) << 3));
  };
  auto RDB = [&](int buf, int cblk, int ks) -> bf16x8 {
    const bf16* h = &sm[buf][1][wn >> 1][0];
    int row = (wn & 1) * 64 + cblk * 32 + l31;
    int gc = ks * 2 + hi;
    return *(const bf16x8*)(h + row * 64 + ((gc ^ (row & 7)) << 3));
  };

  // prologue: issue in steady-state FIFO order (14 loads), drain to 6
  STAGE_AU(0, 0, 0); STAGE_AU(2, 0, 0);
  STAGE_BV(0, 0, 0); STAGE_BV(1, 0, 0);
  STAGE_BV(2, 0, 0); STAGE_BV(3, 0, 0);
  STAGE_AU(1, 0, 0); STAGE_AU(3, 0, 0);
  STAGE_AU(0, 1, 1); STAGE_AU(2, 1, 1);
  STAGE_BV(0, 1, 1); STAGE_BV(1, 1, 1);
  STAGE_BV(2, 1, 1); STAGE_BV(3, 1, 1);
  ASM_VMCNT(6);
  BAR();

  for (int t = 0; t < NT; t++) {
    int cur = t & 1, nxt = cur ^ 1;
    int t1 = (t + 1 < NT) ? t + 1 : NT - 1;
    int t2 = (t + 2 < NT) ? t + 2 : NT - 1;

    // ---- phase 0: read A row-blocks 0-1 + B col-block 0 (12 b128) ----
#pragma unroll
    for (int ks = 0; ks < 4; ks++) {
      af[0][ks] = RDA(cur, 0, ks);
      af[1][ks] = RDA(cur, 1, ks);
      bg[0][ks] = RDB(cur, 0, ks);
    }
    STAGE_AU(1, t1, nxt); STAGE_AU(3, t1, nxt);   // A u1/u3 read @ph2 only
    BAR();
    MM32(0, 0);
    BAR();

    // ---- phase 1: read B col-block 1 (4 b128) ----
#pragma unroll
    for (int ks = 0; ks < 4; ks++) bg[1][ks] = RDB(cur, 1, ks);
    STAGE_AU(0, t2, cur); STAGE_AU(2, t2, cur);   // A u0/u2 freed @ph0
    BAR();
    MM32(0, 1);
    BAR();

    // ---- phase 2: read A row-blocks 2-3 (8 b128) ----
#pragma unroll
    for (int ks = 0; ks < 4; ks++) {
      af[0][ks] = RDA(cur, 2, ks);
      af[1][ks] = RDA(cur, 3, ks);
    }
    STAGE_BV(0, t2, cur); STAGE_BV(1, t2, cur);   // B v0/v1 freed @ph0/ph1
    BAR();
    MM32(1, 0);
    BAR();

    // ---- phase 3: no reads ----
    STAGE_BV(2, t2, cur); STAGE_BV(3, t2, cur);
    BAR();
    MM32(1, 1);
    ASM_VMCNT(6);   // all waves' tile-(t+1) loads visible after the barrier
    BAR();
  }
  ASM_VMCNT(0);

  // epilogue: per-row sum of squares over this wave's 64 cols
  // C/D: col = l31, row = rblk*32 + (reg&3) + 8*(reg>>2) + 4*hi
#pragma unroll
  for (int rblk = 0; rblk < 4; rblk++) {
#pragma unroll
    for (int reg = 0; reg < 16; reg++) {
      float s = 0.f;
#pragma unroll
      for (int cb = 0; cb < 2; cb++) { float v = acc[rblk][cb][reg]; s += v * v; }
      s += __shfl_xor(s, 1);
      s += __shfl_xor(s, 2);
      s += __shfl_xor(s, 4);
      s += __shfl_xor(s, 8);
      s += __shfl_xor(s, 16);
      if (l31 == 0) {
        int row = (int)bm + wm * 128 + rblk * 32 + (reg & 3) + 8 * (reg >> 2) + 4 * hi;
        partial[(size_t)(nt * 4 + wn) * B_DIM + row] = s;
      }
    }
  }
}

// ---------------- finish: sum 64 partials per row, sqrt ----------------
__global__ void k_finish(const float* __restrict__ partial, float* __restrict__ out) {
  int b = blockIdx.x * 256 + threadIdx.x;
  float s = 0.f;
#pragma unroll
  for (int i = 0; i < 64; i++) s += partial[(size_t)i * B_DIM + b];
  out[b] = sqrtf(s);
}

extern "C" void kernel_launch(void* const* d_in, const int* in_sizes, int n_in,
                              void* d_out, int out_size, void* d_ws, size_t ws_size,
                              hipStream_t stream) {
  const float* x  = (const float*)d_in[0];
  const float* hw = (const float*)d_in[1];
  float* out = (float*)d_out;
  char* ws = (char*)d_ws;
  bf16* xb = (bf16*)ws;                                           // 64 MB
  bf16* wt = (bf16*)(ws + (size_t)B_DIM * K_DIM * 2);             // 32 MB
  float* partial = (float*)(ws + (size_t)B_DIM * K_DIM * 2
                               + (size_t)K_DIM * N_DIM * 2);      // 2 MB
  long long R[3];
  mt_randint3(1367u, R);

  k_prep<<<16384 + 16384, 256, 0, stream>>>(x, xb, hw, wt, R[0], R[1], R[2]);
  k_gemm<<<(B_DIM / 256) * (N_DIM / 256), 512, 0, stream>>>(xb, wt, partial);
  k_finish<<<B_DIM / 256, 256, 0, stream>>>(partial, out);
}

// Round 8
// 287.674 us; speedup vs baseline: 1.1546x; 1.1546x over previous
//
#include <hip/hip_runtime.h>
#include <stdint.h>
#include <math.h>

typedef __bf16 bf16;
typedef __bf16 bf16x4 __attribute__((ext_vector_type(4)));
typedef __bf16 bf16x8 __attribute__((ext_vector_type(8)));
typedef float  f32x4  __attribute__((ext_vector_type(4)));

#define B_DIM 8192
#define K_DIM 4096
#define N_DIM 4096
#define MEM_H 1048576
#define HMOD  1047552   // MEM_H - 32*32
#define NT    (K_DIM / 64)

// ---------------- host-side numpy legacy RNG replication ----------------
static void mt_randint3(uint32_t seed, long long R[3]) {
  uint32_t mt[624];
  mt[0] = seed;
  for (int i = 1; i < 624; i++)
    mt[i] = 1812433253u * (mt[i - 1] ^ (mt[i - 1] >> 30)) + (uint32_t)i;
  int pos = 624;
  auto next32 = [&]() -> uint32_t {
    if (pos >= 624) {
      for (int i = 0; i < 624; i++) {
        uint32_t y = (mt[i] & 0x80000000u) | (mt[(i + 1) % 624] & 0x7fffffffu);
        uint32_t v = mt[(i + 397) % 624] ^ (y >> 1);
        if (y & 1u) v ^= 0x9908b0dfu;
        mt[i] = v;
      }
      pos = 0;
    }
    uint32_t y = mt[pos++];
    y ^= y >> 11;
    y ^= (y << 7) & 0x9d2c5680u;
    y ^= (y << 15) & 0xefc60000u;
    y ^= y >> 18;
    return y;
  };
  for (int j = 0; j < 3; j++) {
    uint32_t v;
    do { v = next32() & 0x7fffffffu; } while (v > 0x7ffffffdu);
    R[j] = 1LL + (long long)v;
  }
}

// ---------------- x: f32 -> bf16 (vectorized) ----------------
__global__ void k_convert_x(const float* __restrict__ x, bf16* __restrict__ xb) {
  int i = blockIdx.x * 256 + threadIdx.x;
  const f32x4* p = (const f32x4*)x;
  f32x4 a = p[2 * i], b = p[2 * i + 1];
  bf16x8 o;
  o[0] = (bf16)a[0]; o[1] = (bf16)a[1]; o[2] = (bf16)a[2]; o[3] = (bf16)a[3];
  o[4] = (bf16)b[0]; o[5] = (bf16)b[1]; o[6] = (bf16)b[2]; o[7] = (bf16)b[3];
  ((bf16x8*)xb)[i] = o;
}

// ---------------- build W^T [N][K] bf16 from hashed vector ----------------
__global__ void k_build_wt(const float* __restrict__ hw, bf16* __restrict__ wt,
                           long long R1, long long R2, long long R3) {
  int tile = blockIdx.x;
  int kb = tile & 127, nb = tile >> 7;
  long long v = (long long)kb * R3 + (long long)nb * R2 + R1;
  int start = (int)((v % 2147483647LL) % (long long)HMOD);
  const float* src = hw + start;
  int t  = threadIdx.x;
  int nl = t >> 3;
  int k4 = t & 7;
  bf16x4 o;
#pragma unroll
  for (int j = 0; j < 4; j++) o[j] = (bf16)src[(k4 * 4 + j) * 32 + nl];
  *(bf16x4*)(wt + (size_t)(nb * 32 + nl) * K_DIM + kb * 32 + k4 * 4) = o;
}

// ---------------- 256x256x64 8-phase GEMM, deep prefetch pipeline --------
// Sync invariants:
//  (1) vmcnt is PER-WAVE; counted waits are only meaningful placed BEFORE a
//      barrier (drain own DMA -> barrier makes all waves' landings visible).
//  (2) BARRIER MUST BE THE RAW BUILTIN, not asm-with-memory-clobber: the
//      clobber makes hipcc treat it like __syncthreads and drain vmcnt(0)
//      at every phase, collapsing the prefetch pipeline (R2/R4/R6 ~240us).
__device__ __forceinline__ void gload_lds16(const void* g, void* l) {
  __builtin_amdgcn_global_load_lds(
      (const __attribute__((address_space(1))) void*)g,
      (__attribute__((address_space(3))) void*)l, 16, 0, 0);
}

#define ASM_VMCNT(n) asm volatile("s_waitcnt vmcnt(" #n ")" ::: "memory")
#define BAR() __builtin_amdgcn_s_barrier()

#define MM(rh, ch) do {                                                        \
  __builtin_amdgcn_s_setprio(1);                                               \
  _Pragma("unroll")                                                            \
  for (int ks = 0; ks < 2; ks++)                                               \
    _Pragma("unroll")                                                          \
    for (int r4 = 0; r4 < 4; r4++)                                             \
      _Pragma("unroll")                                                        \
      for (int c2 = 0; c2 < 2; c2++)                                           \
        acc[(rh)*4 + r4][(ch)*2 + c2] =                                        \
            __builtin_amdgcn_mfma_f32_16x16x32_bf16(                           \
                af[r4][ks], bg[(ch)*2 + c2][ks],                               \
                acc[(rh)*4 + r4][(ch)*2 + c2], 0, 0, 0);                       \
  __builtin_amdgcn_s_setprio(0);                                               \
} while (0)

__global__ __launch_bounds__(512, 2) void k_gemm(const bf16* __restrict__ A,
                                                 const bf16* __restrict__ Bt,
                                                 float* __restrict__ partial) {
  // [buf][op 0=A 1=B][half][128*64] : 128 KiB
  __shared__ bf16 sm[2][2][2][128 * 64];
  int bid = blockIdx.x;
  int swz = (bid & 7) * 64 + (bid >> 3);     // 512 blocks, 8 XCDs, bijective
  int mt = swz & 31, nt = swz >> 5;
  int tid = threadIdx.x;
  int w = tid >> 6, lane = tid & 63;
  int wm = w >> 2, wn = w & 3;               // 2 x 4 wave grid, 128x64 each
  int lr = lane & 15, lk = lane >> 4;
  int r8 = lane >> 3, gg = lane & 7;
  int swcol = ((gg ^ r8) << 3);              // pre-swizzled source col (elems)
  size_t bm = (size_t)mt * 256, bn = (size_t)nt * 256;
  const bf16* Ab = A + bm * K_DIM;
  const bf16* Bb = Bt + bn * K_DIM;

  f32x4 acc[8][4] = {};
  bf16x8 af[4][2], bg[4][2];

  // stage one 64-row unit (64 rows x 64 k); each wave stages rows w*8..w*8+7
  auto STAGE_AU = [&](int q, int tt, int buf) {
    gload_lds16(Ab + (size_t)(q * 64 + w * 8 + r8) * K_DIM + tt * 64 + swcol,
                &sm[buf][0][q >> 1][(q & 1) * 4096 + w * 8 * 64]);
  };
  auto STAGE_BV = [&](int j, int tt, int buf) {
    gload_lds16(Bb + (size_t)(j * 64 + w * 8 + r8) * K_DIM + tt * 64 + swcol,
                &sm[buf][1][j >> 1][(j & 1) * 4096 + w * 8 * 64]);
  };
  // swizzled fragment reads
  auto RDA = [&](int buf, int rb, int ks) -> bf16x8 {
    const bf16* h = &sm[buf][0][wm][0];
    int row = rb * 16 + lr;
    int gc = ks * 4 + lk;
    return *(const bf16x8*)(h + row * 64 + ((gc ^ (row & 7)) << 3));
  };
  auto RDB = [&](int buf, int cb, int ks) -> bf16x8 {
    const bf16* h = &sm[buf][1][wn >> 1][0];
    int row = (wn & 1) * 64 + cb * 16 + lr;
    int gc = ks * 4 + lk;
    return *(const bf16x8*)(h + row * 64 + ((gc ^ (row & 7)) << 3));
  };

  // prologue: issue in steady-state FIFO order (14 loads), then drain to 6
  // (= tile 0's 8 loads landed for ALL waves after the barrier)
  STAGE_AU(0, 0, 0); STAGE_AU(2, 0, 0);    // needed t0 ph0
  STAGE_BV(0, 0, 0); STAGE_BV(1, 0, 0);    // needed t0 ph0
  STAGE_BV(2, 0, 0); STAGE_BV(3, 0, 0);    // needed t0 ph0/ph1
  STAGE_AU(1, 0, 0); STAGE_AU(3, 0, 0);    // needed t0 ph2
  STAGE_AU(0, 1, 1); STAGE_AU(2, 1, 1);    // needed t1 ph0
  STAGE_BV(0, 1, 1); STAGE_BV(1, 1, 1);    // needed t1 ph0
  STAGE_BV(2, 1, 1); STAGE_BV(3, 1, 1);    // needed t1 ph0/ph1
  ASM_VMCNT(6);
  BAR();

  for (int t = 0; t < NT; t++) {
    int cur = t & 1, nxt = cur ^ 1;
    int t1 = (t + 1 < NT) ? t + 1 : NT - 1;  // clamped: keeps vmcnt FIFO uniform
    int t2 = (t + 2 < NT) ? t + 2 : NT - 1;

    // ---- phase 0: reads A u0/u2 + B(all units, rows 0-31 of each) ----
#pragma unroll
    for (int rb = 0; rb < 4; rb++) {
      af[rb][0] = RDA(cur, rb, 0);
      af[rb][1] = RDA(cur, rb, 1);
    }
#pragma unroll
    for (int cb = 0; cb < 2; cb++) {
      bg[cb][0] = RDB(cur, cb, 0);
      bg[cb][1] = RDB(cur, cb, 1);
    }
    STAGE_AU(1, t1, nxt); STAGE_AU(3, t1, nxt);   // regions freed @ph2 of t-1
    BAR();
    MM(0, 0);
    BAR();

    // ---- phase 1: reads B rows 32-63 of each unit ----
#pragma unroll
    for (int cb = 2; cb < 4; cb++) {
      bg[cb][0] = RDB(cur, cb, 0);
      bg[cb][1] = RDB(cur, cb, 1);
    }
    STAGE_AU(0, t2, cur); STAGE_AU(2, t2, cur);   // cur A u0/u2 freed @ph0
    BAR();
    MM(0, 1);
    BAR();

    // ---- phase 2: reads A u1/u3 ----
#pragma unroll
    for (int rb = 0; rb < 4; rb++) {
      af[rb][0] = RDA(cur, 4 + rb, 0);
      af[rb][1] = RDA(cur, 4 + rb, 1);
    }
    STAGE_BV(0, t2, cur); STAGE_BV(1, t2, cur);   // cur B freed @ph1
    BAR();
    MM(1, 0);
    BAR();

    // ---- phase 3: no reads ----
    STAGE_BV(2, t2, cur); STAGE_BV(3, t2, cur);
    BAR();
    MM(1, 1);
    // drain so that after the barrier ALL waves' tile-(t+1) loads are in LDS;
    // the 6 newest (ph1-ph3 stages, all for t+2) may stay in flight.
    ASM_VMCNT(6);
    BAR();
  }
  ASM_VMCNT(0);   // drain dummy tail DMA before endpgm

  // epilogue: per-row sum of squares over this wave's 64 cols
  // C frag: col = cb*16 + (lane&15), row = rb*16 + (lane>>4)*4 + reg
#pragma unroll
  for (int rb = 0; rb < 8; rb++) {
#pragma unroll
    for (int reg = 0; reg < 4; reg++) {
      float s = 0.f;
#pragma unroll
      for (int cb = 0; cb < 4; cb++) { float v = acc[rb][cb][reg]; s += v * v; }
      s += __shfl_xor(s, 1);
      s += __shfl_xor(s, 2);
      s += __shfl_xor(s, 4);
      s += __shfl_xor(s, 8);
      if (lr == 0) {
        int row = (int)bm + wm * 128 + rb * 16 + lk * 4 + reg;
        partial[(size_t)(nt * 4 + wn) * B_DIM + row] = s;
      }
    }
  }
}

// ---------------- finish: sum 64 partials per row, sqrt ----------------
__global__ void k_finish(const float* __restrict__ partial, float* __restrict__ out) {
  int b = blockIdx.x * 256 + threadIdx.x;
  float s = 0.f;
#pragma unroll
  for (int i = 0; i < 64; i++) s += partial[(size_t)i * B_DIM + b];
  out[b] = sqrtf(s);
}

extern "C" void kernel_launch(void* const* d_in, const int* in_sizes, int n_in,
                              void* d_out, int out_size, void* d_ws, size_t ws_size,
                              hipStream_t stream) {
  const float* x  = (const float*)d_in[0];
  const float* hw = (const float*)d_in[1];
  float* out = (float*)d_out;
  char* ws = (char*)d_ws;
  bf16* xb = (bf16*)ws;                                           // 64 MB
  bf16* wt = (bf16*)(ws + (size_t)B_DIM * K_DIM * 2);             // 32 MB
  float* partial = (float*)(ws + (size_t)B_DIM * K_DIM * 2
                               + (size_t)K_DIM * N_DIM * 2);      // 2 MB
  long long R[3];
  mt_randint3(1367u, R);

  k_convert_x<<<(B_DIM * K_DIM) / (256 * 8), 256, 0, stream>>>(x, xb);
  k_build_wt<<<(K_DIM / 32) * (N_DIM / 32), 256, 0, stream>>>(hw, wt, R[0], R[1], R[2]);
  k_gemm<<<(B_DIM / 256) * (N_DIM / 256), 512, 0, stream>>>(xb, wt, partial);
  k_finish<<<B_DIM / 256, 256, 0, stream>>>(partial, out);
}

// Round 9
// 287.060 us; speedup vs baseline: 1.1570x; 1.0021x over previous
//
#include <hip/hip_runtime.h>
#include <stdint.h>
#include <math.h>

typedef __bf16 bf16;
typedef __bf16 bf16x4 __attribute__((ext_vector_type(4)));
typedef __bf16 bf16x8 __attribute__((ext_vector_type(8)));
typedef float  f32x4  __attribute__((ext_vector_type(4)));

#define B_DIM 8192
#define K_DIM 4096
#define N_DIM 4096
#define MEM_H 1048576
#define HMOD  1047552   // MEM_H - 32*32
#define NT    (K_DIM / 64)

// ---------------- host-side numpy legacy RNG replication ----------------
static void mt_randint3(uint32_t seed, long long R[3]) {
  uint32_t mt[624];
  mt[0] = seed;
  for (int i = 1; i < 624; i++)
    mt[i] = 1812433253u * (mt[i - 1] ^ (mt[i - 1] >> 30)) + (uint32_t)i;
  int pos = 624;
  auto next32 = [&]() -> uint32_t {
    if (pos >= 624) {
      for (int i = 0; i < 624; i++) {
        uint32_t y = (mt[i] & 0x80000000u) | (mt[(i + 1) % 624] & 0x7fffffffu);
        uint32_t v = mt[(i + 397) % 624] ^ (y >> 1);
        if (y & 1u) v ^= 0x9908b0dfu;
        mt[i] = v;
      }
      pos = 0;
    }
    uint32_t y = mt[pos++];
    y ^= y >> 11;
    y ^= (y << 7) & 0x9d2c5680u;
    y ^= (y << 15) & 0xefc60000u;
    y ^= y >> 18;
    return y;
  };
  for (int j = 0; j < 3; j++) {
    uint32_t v;
    do { v = next32() & 0x7fffffffu; } while (v > 0x7ffffffdu);
    R[j] = 1LL + (long long)v;
  }
}

// ------------- fused pre-pass: convert x AND build W^T -------------------
__global__ void k_prep(const float* __restrict__ x, bf16* __restrict__ xb,
                       const float* __restrict__ hw, bf16* __restrict__ wt,
                       long long R1, long long R2, long long R3) {
  if (blockIdx.x < 16384) {
    int i = blockIdx.x * 256 + threadIdx.x;
    const f32x4* p = (const f32x4*)x;
    f32x4 a = p[2 * i], b = p[2 * i + 1];
    bf16x8 o;
    o[0] = (bf16)a[0]; o[1] = (bf16)a[1]; o[2] = (bf16)a[2]; o[3] = (bf16)a[3];
    o[4] = (bf16)b[0]; o[5] = (bf16)b[1]; o[6] = (bf16)b[2]; o[7] = (bf16)b[3];
    ((bf16x8*)xb)[i] = o;
  } else {
    int tile = blockIdx.x - 16384;
    int kb = tile & 127, nb = tile >> 7;
    long long v = (long long)kb * R3 + (long long)nb * R2 + R1;
    int start = (int)((v % 2147483647LL) % (long long)HMOD);
    const float* src = hw + start;
    int t  = threadIdx.x;
    int nl = t >> 3;
    int k4 = t & 7;
    bf16x4 o;
#pragma unroll
    for (int j = 0; j < 4; j++) o[j] = (bf16)src[(k4 * 4 + j) * 32 + nl];
    *(bf16x4*)(wt + (size_t)(nb * 32 + nl) * K_DIM + kb * 32 + k4 * 4) = o;
  }
}

// ------- 256x256x64 GEMM, 8 waves, read-one-phase-ahead pipeline ---------
// Key change vs R8: ds_reads in phase p load the fragments consumed by the
// MFMA of phase p+1 (register lookahead). The compiler then emits COUNTED
// lgkmcnt waits before each MFMA cluster (only the newer reads outstanding),
// so the LDS pipe serves phase-p reads WHILE the MFMA pipe runs phase-p MM.
// R8's structure had read->consume distance 0 => lgkm full drain per phase
// => LDS (~2050cyc) + MFMA (~2484cyc) fully serialized = measured 4500.
// vmcnt invariant unchanged: counted wait BEFORE a barrier (vmcnt per-wave).
__device__ __forceinline__ void gload_lds16(const void* g, void* l) {
  __builtin_amdgcn_global_load_lds(
      (const __attribute__((address_space(1))) void*)g,
      (__attribute__((address_space(3))) void*)l, 16, 0, 0);
}

#define ASM_VMCNT(n) asm volatile("s_waitcnt vmcnt(" #n ")" ::: "memory")
#define BAR() __builtin_amdgcn_s_barrier()

// MFMA cluster: 16 MFMAs, AF = afE (rows 0-63, acc rows 0-3) or afO (4-7)
#define MMX(rh, ch, AF) do {                                                   \
  __builtin_amdgcn_s_setprio(1);                                               \
  _Pragma("unroll")                                                            \
  for (int ks = 0; ks < 2; ks++)                                               \
    _Pragma("unroll")                                                          \
    for (int r4 = 0; r4 < 4; r4++)                                             \
      _Pragma("unroll")                                                        \
      for (int c2 = 0; c2 < 2; c2++)                                           \
        acc[(rh)*4 + r4][(ch)*2 + c2] =                                        \
            __builtin_amdgcn_mfma_f32_16x16x32_bf16(                           \
                AF[r4][ks], bg[(ch)*2 + c2][ks],                               \
                acc[(rh)*4 + r4][(ch)*2 + c2], 0, 0, 0);                       \
  __builtin_amdgcn_s_setprio(0);                                               \
} while (0)

__global__ __launch_bounds__(512, 2) void k_gemm(const bf16* __restrict__ A,
                                                 const bf16* __restrict__ Bt,
                                                 float* __restrict__ partial) {
  // [buf][op 0=A 1=B][half][128*64] : 128 KiB
  __shared__ bf16 sm[2][2][2][128 * 64];
  int bid = blockIdx.x;
  int swz = (bid & 7) * 64 + (bid >> 3);     // 512 blocks, 8 XCDs, bijective
  int mt = swz & 31, nt = swz >> 5;
  int tid = threadIdx.x;
  int w = tid >> 6, lane = tid & 63;
  int wm = w >> 2, wn = w & 3;               // 2 x 4 wave grid, 128x64 each
  int lr = lane & 15, lk = lane >> 4;
  int r8 = lane >> 3, gg = lane & 7;
  int swcol = ((gg ^ r8) << 3);              // pre-swizzled source col (elems)
  size_t bm = (size_t)mt * 256, bn = (size_t)nt * 256;
  const bf16* Ab = A + bm * K_DIM;
  const bf16* Bb = Bt + bn * K_DIM;

  f32x4 acc[8][4] = {};
  // afE: A rows 0-63 of wave half (rb0-3); afO: rows 64-127 (rb4-7).
  // bg[0..1]: B cols 0-31 slice; bg[2..3]: cols 32-63 slice.
  bf16x8 afE[4][2], afO[4][2], bg[4][2];

  auto STAGE_AU = [&](int q, int tt, int buf) {
    gload_lds16(Ab + (size_t)(q * 64 + w * 8 + r8) * K_DIM + tt * 64 + swcol,
                &sm[buf][0][q >> 1][(q & 1) * 4096 + w * 8 * 64]);
  };
  auto STAGE_BV = [&](int j, int tt, int buf) {
    gload_lds16(Bb + (size_t)(j * 64 + w * 8 + r8) * K_DIM + tt * 64 + swcol,
                &sm[buf][1][j >> 1][(j & 1) * 4096 + w * 8 * 64]);
  };
  auto RDA = [&](int buf, int rb, int ks) -> bf16x8 {
    const bf16* h = &sm[buf][0][wm][0];
    int row = rb * 16 + lr;
    int gc = ks * 4 + lk;
    return *(const bf16x8*)(h + row * 64 + ((gc ^ (row & 7)) << 3));
  };
  auto RDB = [&](int buf, int cb, int ks) -> bf16x8 {
    const bf16* h = &sm[buf][1][wn >> 1][0];
    int row = (wn & 1) * 64 + cb * 16 + lr;
    int gc = ks * 4 + lk;
    return *(const bf16x8*)(h + row * 64 + ((gc ^ (row & 7)) << 3));
  };

  // prologue: 6 "old" t0 loads (drained below) + the exact steady-state
  // 8-deep in-flight set [Au1u3(0), Au0u2(1), Bv0v1(1), Bv2v3(1)].
  STAGE_AU(0, 0, 0); STAGE_AU(2, 0, 0);
  STAGE_BV(0, 0, 0); STAGE_BV(1, 0, 0);
  STAGE_BV(2, 0, 0); STAGE_BV(3, 0, 0);
  STAGE_AU(1, 0, 0); STAGE_AU(3, 0, 0);
  STAGE_AU(0, 1, 1); STAGE_AU(2, 1, 1);
  STAGE_BV(0, 1, 1); STAGE_BV(1, 1, 1);
  STAGE_BV(2, 1, 1); STAGE_BV(3, 1, 1);
  ASM_VMCNT(8);
  BAR();
  // pre-read R0(t0): afE + bg01 from buf0
#pragma unroll
  for (int rb = 0; rb < 4; rb++) {
    afE[rb][0] = RDA(0, rb, 0);
    afE[rb][1] = RDA(0, rb, 1);
  }
#pragma unroll
  for (int cb = 0; cb < 2; cb++) {
    bg[cb][0] = RDB(0, cb, 0);
    bg[cb][1] = RDB(0, cb, 1);
  }

  for (int t = 0; t < NT; t++) {
    int cur = t & 1, nxt = cur ^ 1;
    int t1 = (t + 1 < NT) ? t + 1 : NT - 1;  // clamp keeps vmcnt FIFO uniform
    int t2 = (t + 2 < NT) ? t + 2 : NT - 1;

    // ---- ph0: read R1 (bg23); stage Au1u3(t+1)->nxt; MM(afE,bg01) ----
#pragma unroll
    for (int cb = 2; cb < 4; cb++) {
      bg[cb][0] = RDB(cur, cb, 0);
      bg[cb][1] = RDB(cur, cb, 1);
    }
    STAGE_AU(1, t1, nxt); STAGE_AU(3, t1, nxt);
    ASM_VMCNT(8);                 // drains Au1u3(t) (needed by R2 @ph1)
    BAR();
    MMX(0, 0, afE);
    BAR();

    // ---- ph1: read R2 (afO); stage Au0u2(t+2)->cur; MM(afE,bg23) ----
#pragma unroll
    for (int rb = 0; rb < 4; rb++) {
      afO[rb][0] = RDA(cur, 4 + rb, 0);
      afO[rb][1] = RDA(cur, 4 + rb, 1);
    }
    STAGE_AU(0, t2, cur); STAGE_AU(2, t2, cur);  // A u0/u2 last read @ph3(t-1)
    BAR();
    MMX(0, 1, afE);
    BAR();

    // ---- ph2: no reads; stage Bv0v1(t+2)->cur; MM(afO,bg01) ----
    STAGE_BV(0, t2, cur); STAGE_BV(1, t2, cur);  // B last read @ph0 (R1)
    ASM_VMCNT(6);                 // drains Bv2v3(t+1) (needed by R0 @ph3)
    BAR();
    MMX(1, 0, afO);
    BAR();

    // ---- ph3: read R0(t+1) (afE + bg01 from nxt); stage Bv2v3(t+2)->cur;
    //           MM(afO,bg23) ----
#pragma unroll
    for (int rb = 0; rb < 4; rb++) {
      afE[rb][0] = RDA(nxt, rb, 0);
      afE[rb][1] = RDA(nxt, rb, 1);
    }
#pragma unroll
    for (int cb = 0; cb < 2; cb++) {
      bg[cb][0] = RDB(nxt, cb, 0);
      bg[cb][1] = RDB(nxt, cb, 1);
    }
    STAGE_BV(2, t2, cur); STAGE_BV(3, t2, cur);
    BAR();
    MMX(1, 1, afO);
    BAR();
  }
  ASM_VMCNT(0);   // drain tail DMA before epilogue/endpgm

  // epilogue: per-row sum of squares over this wave's 64 cols
  // C frag: col = cb*16 + (lane&15), row = rb*16 + (lane>>4)*4 + reg
#pragma unroll
  for (int rb = 0; rb < 8; rb++) {
#pragma unroll
    for (int reg = 0; reg < 4; reg++) {
      float s = 0.f;
#pragma unroll
      for (int cb = 0; cb < 4; cb++) { float v = acc[rb][cb][reg]; s += v * v; }
      s += __shfl_xor(s, 1);
      s += __shfl_xor(s, 2);
      s += __shfl_xor(s, 4);
      s += __shfl_xor(s, 8);
      if (lr == 0) {
        int row = (int)bm + wm * 128 + rb * 16 + lk * 4 + reg;
        partial[(size_t)(nt * 4 + wn) * B_DIM + row] = s;
      }
    }
  }
}

// ---------------- finish: sum 64 partials per row, sqrt ----------------
__global__ void k_finish(const float* __restrict__ partial, float* __restrict__ out) {
  int b = blockIdx.x * 256 + threadIdx.x;
  float s = 0.f;
#pragma unroll
  for (int i = 0; i < 64; i++) s += partial[(size_t)i * B_DIM + b];
  out[b] = sqrtf(s);
}

extern "C" void kernel_launch(void* const* d_in, const int* in_sizes, int n_in,
                              void* d_out, int out_size, void* d_ws, size_t ws_size,
                              hipStream_t stream) {
  const float* x  = (const float*)d_in[0];
  const float* hw = (const float*)d_in[1];
  float* out = (float*)d_out;
  char* ws = (char*)d_ws;
  bf16* xb = (bf16*)ws;                                           // 64 MB
  bf16* wt = (bf16*)(ws + (size_t)B_DIM * K_DIM * 2);             // 32 MB
  float* partial = (float*)(ws + (size_t)B_DIM * K_DIM * 2
                               + (size_t)K_DIM * N_DIM * 2);      // 2 MB
  long long R[3];
  mt_randint3(1367u, R);

  k_prep<<<16384 + 16384, 256, 0, stream>>>(x, xb, hw, wt, R[0], R[1], R[2]);
  k_gemm<<<(B_DIM / 256) * (N_DIM / 256), 512, 0, stream>>>(xb, wt, partial);
  k_finish<<<B_DIM / 256, 256, 0, stream>>>(partial, out);
}

// Round 10
// 286.187 us; speedup vs baseline: 1.1606x; 1.0031x over previous
//
#include <hip/hip_runtime.h>
#include <stdint.h>
#include <math.h>

typedef __bf16 bf16;
typedef __bf16 bf16x4 __attribute__((ext_vector_type(4)));
typedef __bf16 bf16x8 __attribute__((ext_vector_type(8)));
typedef float  f32x4  __attribute__((ext_vector_type(4)));

#define B_DIM 8192
#define K_DIM 4096
#define N_DIM 4096
#define MEM_H 1048576
#define HMOD  1047552   // MEM_H - 32*32
#define NT    (K_DIM / 64)

// ---------------- host-side numpy legacy RNG replication ----------------
static void mt_randint3(uint32_t seed, long long R[3]) {
  uint32_t mt[624];
  mt[0] = seed;
  for (int i = 1; i < 624; i++)
    mt[i] = 1812433253u * (mt[i - 1] ^ (mt[i - 1] >> 30)) + (uint32_t)i;
  int pos = 624;
  auto next32 = [&]() -> uint32_t {
    if (pos >= 624) {
      for (int i = 0; i < 624; i++) {
        uint32_t y = (mt[i] & 0x80000000u) | (mt[(i + 1) % 624] & 0x7fffffffu);
        uint32_t v = mt[(i + 397) % 624] ^ (y >> 1);
        if (y & 1u) v ^= 0x9908b0dfu;
        mt[i] = v;
      }
      pos = 0;
    }
    uint32_t y = mt[pos++];
    y ^= y >> 11;
    y ^= (y << 7) & 0x9d2c5680u;
    y ^= (y << 15) & 0xefc60000u;
    y ^= y >> 18;
    return y;
  };
  for (int j = 0; j < 3; j++) {
    uint32_t v;
    do { v = next32() & 0x7fffffffu; } while (v > 0x7ffffffdu);
    R[j] = 1LL + (long long)v;
  }
}

// ------------- fused pre-pass: convert x AND build W^T -------------------
__global__ void k_prep(const float* __restrict__ x, bf16* __restrict__ xb,
                       const float* __restrict__ hw, bf16* __restrict__ wt,
                       long long R1, long long R2, long long R3) {
  if (blockIdx.x < 16384) {
    int i = blockIdx.x * 256 + threadIdx.x;
    const f32x4* p = (const f32x4*)x;
    f32x4 a = p[2 * i], b = p[2 * i + 1];
    bf16x8 o;
    o[0] = (bf16)a[0]; o[1] = (bf16)a[1]; o[2] = (bf16)a[2]; o[3] = (bf16)a[3];
    o[4] = (bf16)b[0]; o[5] = (bf16)b[1]; o[6] = (bf16)b[2]; o[7] = (bf16)b[3];
    ((bf16x8*)xb)[i] = o;
  } else {
    int tile = blockIdx.x - 16384;
    int kb = tile & 127, nb = tile >> 7;
    long long v = (long long)kb * R3 + (long long)nb * R2 + R1;
    int start = (int)((v % 2147483647LL) % (long long)HMOD);
    const float* src = hw + start;
    int t  = threadIdx.x;
    int nl = t >> 3;
    int k4 = t & 7;
    bf16x4 o;
#pragma unroll
    for (int j = 0; j < 4; j++) o[j] = (bf16)src[(k4 * 4 + j) * 32 + nl];
    *(bf16x4*)(wt + (size_t)(nb * 32 + nl) * K_DIM + kb * 32 + k4 * 4) = o;
  }
}

// ------- 256x256x64 GEMM: exact m201 8-phase micro-pattern ---------------
// Per phase: {ds_read for THIS phase's MM; stage; [lgkmcnt(8) on 12-read
// phase]; s_barrier; s_waitcnt lgkmcnt(0) (NO memory clobber); setprio(1);
// 16 MFMA; setprio(0); s_barrier}. Counted vmcnt(6) once per K-tile before
// the tile's last barrier, also clobber-free. Staging placement and the
// vmcnt FIFO ledger are R4's (numerically verified).
__device__ __forceinline__ void gload_lds16(const void* g, void* l) {
  __builtin_amdgcn_global_load_lds(
      (const __attribute__((address_space(1))) void*)g,
      (__attribute__((address_space(3))) void*)l, 16, 0, 0);
}

#define ASM_VMCNT(n) asm volatile("s_waitcnt vmcnt(" #n ")")
#define ASM_LGKM(n)  asm volatile("s_waitcnt lgkmcnt(" #n ")")
#define BAR() __builtin_amdgcn_s_barrier()

#define MM(rh, ch) do {                                                        \
  __builtin_amdgcn_s_setprio(1);                                               \
  _Pragma("unroll")                                                            \
  for (int ks = 0; ks < 2; ks++)                                               \
    _Pragma("unroll")                                                          \
    for (int r4 = 0; r4 < 4; r4++)                                             \
      _Pragma("unroll")                                                        \
      for (int c2 = 0; c2 < 2; c2++)                                           \
        acc[(rh)*4 + r4][(ch)*2 + c2] =                                        \
            __builtin_amdgcn_mfma_f32_16x16x32_bf16(                           \
                af[r4][ks], bg[(ch)*2 + c2][ks],                               \
                acc[(rh)*4 + r4][(ch)*2 + c2], 0, 0, 0);                       \
  __builtin_amdgcn_s_setprio(0);                                               \
} while (0)

__global__ __launch_bounds__(512, 2) void k_gemm(const bf16* __restrict__ A,
                                                 const bf16* __restrict__ Bt,
                                                 float* __restrict__ partial) {
  // [buf][op 0=A 1=B][half][128*64] : 128 KiB
  __shared__ bf16 sm[2][2][2][128 * 64];
  int bid = blockIdx.x;
  int swz = (bid & 7) * 64 + (bid >> 3);     // 512 blocks, 8 XCDs, bijective
  int mt = swz & 31, nt = swz >> 5;
  int tid = threadIdx.x;
  int w = tid >> 6, lane = tid & 63;
  int wm = w >> 2, wn = w & 3;               // 2 x 4 wave grid, 128x64 each
  int lr = lane & 15, lk = lane >> 4;
  int r8 = lane >> 3, gg = lane & 7;
  int swcol = ((gg ^ r8) << 3);              // pre-swizzled source col (elems)
  size_t bm = (size_t)mt * 256, bn = (size_t)nt * 256;
  const bf16* Ab = A + bm * K_DIM;
  const bf16* Bb = Bt + bn * K_DIM;

  f32x4 acc[8][4] = {};
  bf16x8 af[4][2], bg[4][2];

  // stage one 64-row unit (64 rows x 64 k); each wave stages rows w*8..w*8+7
  auto STAGE_AU = [&](int q, int tt, int buf) {
    gload_lds16(Ab + (size_t)(q * 64 + w * 8 + r8) * K_DIM + tt * 64 + swcol,
                &sm[buf][0][q >> 1][(q & 1) * 4096 + w * 8 * 64]);
  };
  auto STAGE_BV = [&](int j, int tt, int buf) {
    gload_lds16(Bb + (size_t)(j * 64 + w * 8 + r8) * K_DIM + tt * 64 + swcol,
                &sm[buf][1][j >> 1][(j & 1) * 4096 + w * 8 * 64]);
  };
  // swizzled fragment reads
  auto RDA = [&](int buf, int rb, int ks) -> bf16x8 {
    const bf16* h = &sm[buf][0][wm][0];
    int row = rb * 16 + lr;
    int gc = ks * 4 + lk;
    return *(const bf16x8*)(h + row * 64 + ((gc ^ (row & 7)) << 3));
  };
  auto RDB = [&](int buf, int cb, int ks) -> bf16x8 {
    const bf16* h = &sm[buf][1][wn >> 1][0];
    int row = (wn & 1) * 64 + cb * 16 + lr;
    int gc = ks * 4 + lk;
    return *(const bf16x8*)(h + row * 64 + ((gc ^ (row & 7)) << 3));
  };

  // prologue: 14 loads in steady-state FIFO order; vmcnt(6)+BAR drains the
  // 8 oldest (= all of tile 0) for ALL waves.
  STAGE_AU(0, 0, 0); STAGE_AU(2, 0, 0);
  STAGE_BV(0, 0, 0); STAGE_BV(1, 0, 0);
  STAGE_BV(2, 0, 0); STAGE_BV(3, 0, 0);
  STAGE_AU(1, 0, 0); STAGE_AU(3, 0, 0);
  STAGE_AU(0, 1, 1); STAGE_AU(2, 1, 1);
  STAGE_BV(0, 1, 1); STAGE_BV(1, 1, 1);
  STAGE_BV(2, 1, 1); STAGE_BV(3, 1, 1);
  ASM_VMCNT(6);
  BAR();

  for (int t = 0; t < NT; t++) {
    int cur = t & 1, nxt = cur ^ 1;
    int t1 = (t + 1 < NT) ? t + 1 : NT - 1;  // clamp keeps vmcnt FIFO uniform
    int t2 = (t + 2 < NT) ? t + 2 : NT - 1;

    // ---- ph0: 12 reads (af rb0-3 = Au0/u2, bg cb0-1); stage Au1u3(t+1) ----
#pragma unroll
    for (int rb = 0; rb < 4; rb++) {
      af[rb][0] = RDA(cur, rb, 0);
      af[rb][1] = RDA(cur, rb, 1);
    }
#pragma unroll
    for (int cb = 0; cb < 2; cb++) {
      bg[cb][0] = RDB(cur, cb, 0);
      bg[cb][1] = RDB(cur, cb, 1);
    }
    STAGE_AU(1, t1, nxt); STAGE_AU(3, t1, nxt);   // regions freed @ph2 of t-1
    ASM_LGKM(8);
    BAR();
    ASM_LGKM(0);
    MM(0, 0);
    BAR();

    // ---- ph1: 4 reads (bg cb2-3); stage Au0u2(t+2)->cur (freed @ph0) ----
#pragma unroll
    for (int cb = 2; cb < 4; cb++) {
      bg[cb][0] = RDB(cur, cb, 0);
      bg[cb][1] = RDB(cur, cb, 1);
    }
    STAGE_AU(0, t2, cur); STAGE_AU(2, t2, cur);
    BAR();
    ASM_LGKM(0);
    MM(0, 1);
    BAR();

    // ---- ph2: 8 reads (af rb4-7 = Au1/u3); stage Bv0v1(t+2)->cur ----
#pragma unroll
    for (int rb = 0; rb < 4; rb++) {
      af[rb][0] = RDA(cur, 4 + rb, 0);
      af[rb][1] = RDA(cur, 4 + rb, 1);
    }
    STAGE_BV(0, t2, cur); STAGE_BV(1, t2, cur);   // cur B fully read @ph1
    BAR();
    ASM_LGKM(0);
    MM(1, 0);
    BAR();

    // ---- ph3: no reads; stage Bv2v3(t+2)->cur; tile-boundary vmcnt ----
    STAGE_BV(2, t2, cur); STAGE_BV(3, t2, cur);
    BAR();
    MM(1, 1);
    // drain so all waves' tile-(t+1) loads are in LDS after the barrier;
    // the 6 newest (ph1-ph3 stages, all t+2) stay in flight.
    ASM_VMCNT(6);
    BAR();
  }
  ASM_VMCNT(0);   // drain tail DMA before epilogue/endpgm

  // epilogue: per-row sum of squares over this wave's 64 cols
  // C frag: col = cb*16 + (lane&15), row = rb*16 + (lane>>4)*4 + reg
#pragma unroll
  for (int rb = 0; rb < 8; rb++) {
#pragma unroll
    for (int reg = 0; reg < 4; reg++) {
      float s = 0.f;
#pragma unroll
      for (int cb = 0; cb < 4; cb++) { float v = acc[rb][cb][reg]; s += v * v; }
      s += __shfl_xor(s, 1);
      s += __shfl_xor(s, 2);
      s += __shfl_xor(s, 4);
      s += __shfl_xor(s, 8);
      if (lr == 0) {
        int row = (int)bm + wm * 128 + rb * 16 + lk * 4 + reg;
        partial[(size_t)(nt * 4 + wn) * B_DIM + row] = s;
      }
    }
  }
}

// ---------------- finish: sum 64 partials per row, sqrt ----------------
__global__ void k_finish(const float* __restrict__ partial, float* __restrict__ out) {
  int b = blockIdx.x * 256 + threadIdx.x;
  float s = 0.f;
#pragma unroll
  for (int i = 0; i < 64; i++) s += partial[(size_t)i * B_DIM + b];
  out[b] = sqrtf(s);
}

extern "C" void kernel_launch(void* const* d_in, const int* in_sizes, int n_in,
                              void* d_out, int out_size, void* d_ws, size_t ws_size,
                              hipStream_t stream) {
  const float* x  = (const float*)d_in[0];
  const float* hw = (const float*)d_in[1];
  float* out = (float*)d_out;
  char* ws = (char*)d_ws;
  bf16* xb = (bf16*)ws;                                           // 64 MB
  bf16* wt = (bf16*)(ws + (size_t)B_DIM * K_DIM * 2);             // 32 MB
  float* partial = (float*)(ws + (size_t)B_DIM * K_DIM * 2
                               + (size_t)K_DIM * N_DIM * 2);      // 2 MB
  long long R[3];
  mt_randint3(1367u, R);

  k_prep<<<16384 + 16384, 256, 0, stream>>>(x, xb, hw, wt, R[0], R[1], R[2]);
  k_gemm<<<(B_DIM / 256) * (N_DIM / 256), 512, 0, stream>>>(xb, wt, partial);
  k_finish<<<B_DIM / 256, 256, 0, stream>>>(partial, out);
}

// Round 11
// 277.034 us; speedup vs baseline: 1.1989x; 1.0330x over previous
//
#include <hip/hip_runtime.h>
#include <stdint.h>
#include <math.h>

typedef __bf16 bf16;
typedef __bf16 bf16x4 __attribute__((ext_vector_type(4)));
typedef __bf16 bf16x8 __attribute__((ext_vector_type(8)));
typedef float  f32x4  __attribute__((ext_vector_type(4)));

#define B_DIM 8192
#define K_DIM 4096
#define N_DIM 4096
#define MEM_H 1048576
#define HMOD  1047552   // MEM_H - 32*32
#define NT    (K_DIM / 64)

// ---------------- host-side numpy legacy RNG replication ----------------
static void mt_randint3(uint32_t seed, long long R[3]) {
  uint32_t mt[624];
  mt[0] = seed;
  for (int i = 1; i < 624; i++)
    mt[i] = 1812433253u * (mt[i - 1] ^ (mt[i - 1] >> 30)) + (uint32_t)i;
  int pos = 624;
  auto next32 = [&]() -> uint32_t {
    if (pos >= 624) {
      for (int i = 0; i < 624; i++) {
        uint32_t y = (mt[i] & 0x80000000u) | (mt[(i + 1) % 624] & 0x7fffffffu);
        uint32_t v = mt[(i + 397) % 624] ^ (y >> 1);
        if (y & 1u) v ^= 0x9908b0dfu;
        mt[i] = v;
      }
      pos = 0;
    }
    uint32_t y = mt[pos++];
    y ^= y >> 11;
    y ^= (y << 7) & 0x9d2c5680u;
    y ^= (y << 15) & 0xefc60000u;
    y ^= y >> 18;
    return y;
  };
  for (int j = 0; j < 3; j++) {
    uint32_t v;
    do { v = next32() & 0x7fffffffu; } while (v > 0x7ffffffdu);
    R[j] = 1LL + (long long)v;
  }
}

// ------------- fused pre-pass: convert x AND build W^T -------------------
__global__ void k_prep(const float* __restrict__ x, bf16* __restrict__ xb,
                       const float* __restrict__ hw, bf16* __restrict__ wt,
                       long long R1, long long R2, long long R3) {
  if (blockIdx.x < 16384) {
    int i = blockIdx.x * 256 + threadIdx.x;
    const f32x4* p = (const f32x4*)x;
    f32x4 a = p[2 * i], b = p[2 * i + 1];
    bf16x8 o;
    o[0] = (bf16)a[0]; o[1] = (bf16)a[1]; o[2] = (bf16)a[2]; o[3] = (bf16)a[3];
    o[4] = (bf16)b[0]; o[5] = (bf16)b[1]; o[6] = (bf16)b[2]; o[7] = (bf16)b[3];
    ((bf16x8*)xb)[i] = o;
  } else {
    int tile = blockIdx.x - 16384;
    int kb = tile & 127, nb = tile >> 7;
    long long v = (long long)kb * R3 + (long long)nb * R2 + R1;
    int start = (int)((v % 2147483647LL) % (long long)HMOD);
    const float* src = hw + start;
    int t  = threadIdx.x;
    int nl = t >> 3;
    int k4 = t & 7;
    bf16x4 o;
#pragma unroll
    for (int j = 0; j < 4; j++) o[j] = (bf16)src[(k4 * 4 + j) * 32 + nl];
    *(bf16x4*)(wt + (size_t)(nb * 32 + nl) * K_DIM + kb * 32 + k4 * 4) = o;
  }
}

// ---- 256x256x64 GEMM: asm ds_read + counted lgkm, reads inside MFMA ----
// Mechanism: reads for phase p+1's MFMA are issued (inline asm, no compiler
// waits) in the middle of phase p's MFMA cluster; the ONLY lgkm waits are
// my counted ones at phase tops -> LDS service overlaps the MFMA pipe.
// R3-invariant honored: every read of DMA-staged data sits >=1 BARRIER
// after the per-wave vmcnt drain of that data (vmcnt is per-wave!).
__device__ __forceinline__ void gload_lds16(const void* g, void* l) {
  __builtin_amdgcn_global_load_lds(
      (const __attribute__((address_space(1))) void*)g,
      (__attribute__((address_space(3))) void*)l, 16, 0, 0);
}

#define SGB() __builtin_amdgcn_sched_barrier(0)
#define VMC(n)  do { SGB(); asm volatile("s_waitcnt vmcnt(" #n ")"); SGB(); } while (0)
#define LGKM(n) do { SGB(); asm volatile("s_waitcnt lgkmcnt(" #n ")"); SGB(); } while (0)
#define BAR() __builtin_amdgcn_s_barrier()
#define DSR(dst, base, off) \
  asm volatile("ds_read_b128 %0, %1 offset:" off : "=&v"(dst) : "v"(base))

#define FM(RH, R4, CB, KS, AF)                                                 \
  acc[(RH)*4 + (R4)][CB] = __builtin_amdgcn_mfma_f32_16x16x32_bf16(            \
      AF[R4][KS], bg[CB][KS], acc[(RH)*4 + (R4)][CB], 0, 0, 0)
#define FM4(RH, CB, KS, AF) do {                                               \
  FM(RH, 0, CB, KS, AF); FM(RH, 1, CB, KS, AF);                                \
  FM(RH, 2, CB, KS, AF); FM(RH, 3, CB, KS, AF); } while (0)

__global__ __launch_bounds__(512, 2) void k_gemm(const bf16* __restrict__ A,
                                                 const bf16* __restrict__ Bt,
                                                 float* __restrict__ partial) {
  // [buf][op 0=A 1=B][half][128*64] : 128 KiB
  __shared__ bf16 sm[2][2][2][128 * 64];
  int bid = blockIdx.x;
  int swz = (bid & 7) * 64 + (bid >> 3);     // 512 blocks, 8 XCDs, bijective
  int mt = swz & 31, nt = swz >> 5;
  int tid = threadIdx.x;
  int w = tid >> 6, lane = tid & 63;
  int wm = w >> 2, wn = w & 3;               // 2 x 4 wave grid, 128x64 each
  int lr = lane & 15, lk = lane >> 4;
  int r8 = lane >> 3, gg = lane & 7;
  int swcol = ((gg ^ r8) << 3);              // pre-swizzled source col (elems)
  size_t bm = (size_t)mt * 256, bn = (size_t)nt * 256;
  const bf16* Ab = A + bm * K_DIM;
  const bf16* Bb = Bt + bn * K_DIM;

  f32x4 acc[8][4] = {};
  // afE: A rows 0-63 of wave half; afO: rows 64-127; bg[0..1]: B cols *..+31
  // within wave's unit; bg[2..3]: cols +32..63. [frag][ks]
  bf16x8 afE[4][2], afO[4][2], bg[4][2];

  auto STAGE_AU = [&](int q, int tt, int buf) {
    gload_lds16(Ab + (size_t)(q * 64 + w * 8 + r8) * K_DIM + tt * 64 + swcol,
                &sm[buf][0][q >> 1][(q & 1) * 4096 + w * 8 * 64]);
  };
  auto STAGE_BV = [&](int j, int tt, int buf) {
    gload_lds16(Bb + (size_t)(j * 64 + w * 8 + r8) * K_DIM + tt * 64 + swcol,
                &sm[buf][1][j >> 1][(j & 1) * 4096 + w * 8 * 64]);
  };

  // LDS byte-offset bases for asm ds_read (buf0). A frag (rb,ks):
  // addr = base + wm*16384 + (rb*16+lr)*128 + ((ks*4+lk)^(lr&7))*16
  //      = aA{ks} + rb*2048.  B frag (cb,ks): aB{ks} + cb*2048.
  uint32_t smb = (uint32_t)(uintptr_t)
      (__attribute__((address_space(3))) bf16*)&sm[0][0][0][0];
  uint32_t ax0 = (uint32_t)(((lk) ^ (lr & 7)) << 4);
  uint32_t ax1 = (uint32_t)(((4 + lk) ^ (lr & 7)) << 4);
  uint32_t aA0 = smb + wm * 16384 + lr * 128 + ax0;
  uint32_t aA1 = smb + wm * 16384 + lr * 128 + ax1;
  uint32_t aB0 = smb + 32768 + (wn >> 1) * 16384 + ((wn & 1) * 64 + lr) * 128 + ax0;
  uint32_t aB1 = smb + 32768 + (wn >> 1) * 16384 + ((wn & 1) * 64 + lr) * 128 + ax1;

  // prologue: 14 stages in steady FIFO order; vmcnt(6)+BAR lands tile 0 for
  // ALL waves; then pre-read R(ph0,t0) = afE(0) + bg01(0) from buf0.
  STAGE_AU(0, 0, 0); STAGE_AU(2, 0, 0);
  STAGE_AU(1, 0, 0); STAGE_AU(3, 0, 0);
  STAGE_BV(0, 0, 0); STAGE_BV(1, 0, 0);
  STAGE_BV(2, 0, 0); STAGE_BV(3, 0, 0);
  STAGE_AU(0, 1, 1); STAGE_AU(2, 1, 1);
  STAGE_BV(0, 1, 1); STAGE_BV(1, 1, 1);
  STAGE_BV(2, 1, 1); STAGE_BV(3, 1, 1);
  VMC(6);
  BAR();
  DSR(afE[0][0], aA0, "0");    DSR(afE[0][1], aA1, "0");
  DSR(afE[1][0], aA0, "2048"); DSR(afE[1][1], aA1, "2048");
  DSR(afE[2][0], aA0, "4096"); DSR(afE[2][1], aA1, "4096");
  DSR(afE[3][0], aA0, "6144"); DSR(afE[3][1], aA1, "6144");
  DSR(bg[0][0], aB0, "0");     DSR(bg[0][1], aB1, "0");
  DSR(bg[1][0], aB0, "2048");  DSR(bg[1][1], aB1, "2048");

  for (int t = 0; t < NT; t++) {
    int t1 = (t + 1 < NT) ? t + 1 : NT - 1;  // clamp keeps vmcnt FIFO uniform
    int t2 = (t + 2 < NT) ? t + 2 : NT - 1;
    int cur = t & 1, nxt = cur ^ 1;
    uint32_t bsel = (uint32_t)cur << 16;
    uint32_t A0c = aA0 + bsel, A1c = aA1 + bsel;
    uint32_t B0c = aB0 + bsel, B1c = aB1 + bsel;
    uint32_t A0n = A0c ^ 65536u, A1n = A1c ^ 65536u;
    uint32_t B0n = B0c ^ 65536u, B1n = B1c ^ 65536u;

    // ---- ph0: MM(afE, bg01); mid-reads bg23(cur); stage A13(t1)->nxt ----
    LGKM(0);                      // afE(t)+bg01(t), serviced during ph3(t-1)
    __builtin_amdgcn_s_setprio(1);
    FM4(0, 0, 0, afE);
    SGB();
    DSR(bg[2][0], B0c, "4096");  DSR(bg[2][1], B1c, "4096");
    DSR(bg[3][0], B0c, "6144");  DSR(bg[3][1], B1c, "6144");
    SGB();
    FM4(0, 1, 0, afE); FM4(0, 0, 1, afE); FM4(0, 1, 1, afE);
    __builtin_amdgcn_s_setprio(0);
    STAGE_AU(1, t1, nxt); STAGE_AU(3, t1, nxt);
    VMC(8);                       // drains A13(t) for THIS wave
    BAR();                        // ...and the BAR makes it mutual

    // ---- ph1: MM(afE, bg23); mid-reads afO(cur); stage A02(t2)->cur ----
    LGKM(0);                      // bg23(t), serviced during ph0 MFMA tail
    __builtin_amdgcn_s_setprio(1);
    FM4(0, 2, 0, afE);
    SGB();
    DSR(afO[0][0], A0c, "8192");  DSR(afO[0][1], A1c, "8192");
    DSR(afO[1][0], A0c, "10240"); DSR(afO[1][1], A1c, "10240");
    DSR(afO[2][0], A0c, "12288"); DSR(afO[2][1], A1c, "12288");
    DSR(afO[3][0], A0c, "14336"); DSR(afO[3][1], A1c, "14336");
    SGB();
    FM4(0, 3, 0, afE); FM4(0, 2, 1, afE); FM4(0, 3, 1, afE);
    __builtin_amdgcn_s_setprio(0);
    STAGE_AU(0, t2, cur); STAGE_AU(2, t2, cur);  // cur A-u0u2 free since ph3(t-1)
    BAR();

    // ---- ph2: MM(afO, bg01); stage B01(t2)->cur; tile-(t+1) drain ----
    LGKM(0);                      // afO(t), serviced during ph1 MFMA tail
    __builtin_amdgcn_s_setprio(1);
    FM4(1, 0, 0, afO);
    FM4(1, 1, 0, afO); FM4(1, 0, 1, afO); FM4(1, 1, 1, afO);
    __builtin_amdgcn_s_setprio(0);
    STAGE_BV(0, t2, cur); STAGE_BV(1, t2, cur);  // cur B01 free since ph3(t-1)
    VMC(6);                       // drains A02/B01/B23(t+1) for THIS wave
    BAR();                        // mutual -> nxt readable from ph3 on

    // ---- ph3: MM(afO, bg23); mid-reads afE+bg01(nxt,t+1); stage B23 ----
    __builtin_amdgcn_s_setprio(1);   // no lgkm: afO/bg23 already waited
    FM4(1, 2, 0, afO);
    SGB();
    DSR(afE[0][0], A0n, "0");    DSR(afE[0][1], A1n, "0");
    DSR(afE[1][0], A0n, "2048"); DSR(afE[1][1], A1n, "2048");
    DSR(afE[2][0], A0n, "4096"); DSR(afE[2][1], A1n, "4096");
    DSR(afE[3][0], A0n, "6144"); DSR(afE[3][1], A1n, "6144");
    DSR(bg[0][0], B0n, "0");     DSR(bg[0][1], B1n, "0");
    DSR(bg[1][0], B0n, "2048");  DSR(bg[1][1], B1n, "2048");
    SGB();
    FM4(1, 3, 0, afO); FM4(1, 2, 1, afO); FM4(1, 3, 1, afO);
    __builtin_amdgcn_s_setprio(0);
    STAGE_BV(2, t2, cur); STAGE_BV(3, t2, cur);  // cur B23 free since ph0
    BAR();
  }
  VMC(0);
  LGKM(0);   // drain dangling tail reads/DMA before epilogue

  // epilogue: per-row sum of squares over this wave's 64 cols
  // C frag: col = cb*16 + (lane&15), row = rb*16 + (lane>>4)*4 + reg
#pragma unroll
  for (int rb = 0; rb < 8; rb++) {
#pragma unroll
    for (int reg = 0; reg < 4; reg++) {
      float s = 0.f;
#pragma unroll
      for (int cb = 0; cb < 4; cb++) { float v = acc[rb][cb][reg]; s += v * v; }
      s += __shfl_xor(s, 1);
      s += __shfl_xor(s, 2);
      s += __shfl_xor(s, 4);
      s += __shfl_xor(s, 8);
      if (lr == 0) {
        int row = (int)bm + wm * 128 + rb * 16 + lk * 4 + reg;
        partial[(size_t)(nt * 4 + wn) * B_DIM + row] = s;
      }
    }
  }
}

// ---------------- finish: sum 64 partials per row, sqrt ----------------
__global__ void k_finish(const float* __restrict__ partial, float* __restrict__ out) {
  int b = blockIdx.x * 256 + threadIdx.x;
  float s = 0.f;
#pragma unroll
  for (int i = 0; i < 64; i++) s += partial[(size_t)i * B_DIM + b];
  out[b] = sqrtf(s);
}

extern "C" void kernel_launch(void* const* d_in, const int* in_sizes, int n_in,
                              void* d_out, int out_size, void* d_ws, size_t ws_size,
                              hipStream_t stream) {
  const float* x  = (const float*)d_in[0];
  const float* hw = (const float*)d_in[1];
  float* out = (float*)d_out;
  char* ws = (char*)d_ws;
  bf16* xb = (bf16*)ws;                                           // 64 MB
  bf16* wt = (bf16*)(ws + (size_t)B_DIM * K_DIM * 2);             // 32 MB
  float* partial = (float*)(ws + (size_t)B_DIM * K_DIM * 2
                               + (size_t)K_DIM * N_DIM * 2);      // 2 MB
  long long R[3];
  mt_randint3(1367u, R);

  k_prep<<<16384 + 16384, 256, 0, stream>>>(x, xb, hw, wt, R[0], R[1], R[2]);
  k_gemm<<<(B_DIM / 256) * (N_DIM / 256), 512, 0, stream>>>(xb, wt, partial);
  k_finish<<<B_DIM / 256, 256, 0, stream>>>(partial, out);
}

// Round 12
// 233.011 us; speedup vs baseline: 1.4254x; 1.1889x over previous
//
#include <hip/hip_runtime.h>
#include <stdint.h>
#include <math.h>

typedef __bf16 bf16;
typedef float f32x4 __attribute__((ext_vector_type(4)));

#define B_DIM 8192
#define K_DIM 4096
#define N_DIM 4096
#define MEM_H 1048576
#define HMOD  1047552   // MEM_H - 32*32
#define NT    (K_DIM / 64)

// ---------------- host-side numpy legacy RNG replication ----------------
static void mt_randint3(uint32_t seed, long long R[3]) {
  uint32_t mt[624];
  mt[0] = seed;
  for (int i = 1; i < 624; i++)
    mt[i] = 1812433253u * (mt[i - 1] ^ (mt[i - 1] >> 30)) + (uint32_t)i;
  int pos = 624;
  auto next32 = [&]() -> uint32_t {
    if (pos >= 624) {
      for (int i = 0; i < 624; i++) {
        uint32_t y = (mt[i] & 0x80000000u) | (mt[(i + 1) % 624] & 0x7fffffffu);
        uint32_t v = mt[(i + 397) % 624] ^ (y >> 1);
        if (y & 1u) v ^= 0x9908b0dfu;
        mt[i] = v;
      }
      pos = 0;
    }
    uint32_t y = mt[pos++];
    y ^= y >> 11;
    y ^= (y << 7) & 0x9d2c5680u;
    y ^= (y << 15) & 0xefc60000u;
    y ^= y >> 18;
    return y;
  };
  for (int j = 0; j < 3; j++) {
    uint32_t v;
    do { v = next32() & 0x7fffffffu; } while (v > 0x7ffffffdu);
    R[j] = 1LL + (long long)v;
  }
}

// ---------------- f32 -> OCP e4m3fn, RTN-even, with subnormals ----------
__device__ __forceinline__ uint32_t f2e4m3(float f) {
  uint32_t u = __float_as_uint(f);
  uint32_t s = (u >> 24) & 0x80u;
  float a = fabsf(f);
  uint32_t b;
  if (a < 0.015625f) {
    b = (uint32_t)(int)rintf(a * 512.0f);        // 0..8 ; 8 == 2^-6 normal
  } else {
    uint32_t au = __float_as_uint(a);
    au += 0x7FFFFu + ((au >> 20) & 1u);          // round mantissa to 3 bits
    int E = (int)(au >> 23) - 127;
    if (E > 8) b = 0x7Eu;                        // saturate to 448
    else b = (uint32_t)(((E + 7) << 3) | ((au >> 20) & 7u));
  }
  return b | s;
}

// -------- fused pre-pass: quantize x AND build W^T (scaled x64) ---------
__global__ void k_prep(const float* __restrict__ x, uint8_t* __restrict__ xq,
                       const float* __restrict__ hw, uint8_t* __restrict__ wq,
                       long long R1, long long R2, long long R3) {
  if (blockIdx.x < 8192) {
    int i = blockIdx.x * 256 + threadIdx.x;      // 16 elems/thread
    const f32x4* p = (const f32x4*)x;
    uint32_t r[4];
#pragma unroll
    for (int j = 0; j < 4; j++) {
      f32x4 v = p[i * 4 + j];
      r[j] = f2e4m3(v[0]) | (f2e4m3(v[1]) << 8) |
             (f2e4m3(v[2]) << 16) | (f2e4m3(v[3]) << 24);
    }
    ((uint4*)xq)[i] = make_uint4(r[0], r[1], r[2], r[3]);
  } else {
    int tile = blockIdx.x - 8192;
    int kb = tile & 127, nb = tile >> 7;
    long long v = (long long)kb * R3 + (long long)nb * R2 + R1;
    int start = (int)((v % 2147483647LL) % (long long)HMOD);
    const float* src = hw + start;
    int t = threadIdx.x;
    int nl = t >> 3, k4 = t & 7;
    uint32_t b = 0;
#pragma unroll
    for (int j = 0; j < 4; j++)
      b |= f2e4m3(src[(k4 * 4 + j) * 32 + nl] * 64.0f) << (8 * j);
    *(uint32_t*)(wq + (size_t)(nb * 32 + nl) * 4096 + kb * 32 + k4 * 4) = b;
  }
}

// ---- 256x256x64 fp8 GEMM: R11 skeleton, bytes halved -------------------
// LDS 64KB. Per tile: 4 DMA/wave (A halves x2, B halves x2), 24 ds_read_b64
// per wave. Swizzle: 8B granule g at LDS pos g^(row&6) (even XOR keeps the
// DMA's 16B lane-chunks contiguous; read side applies the same XOR).
// Ledger: stages ph2: B(t+2)->cur, ph3: A(t+2)->cur. Single VMC(2) at
// end-ph2 drains {B(t+1),A(t+1)} (issued 4 phases earlier). Overwrites:
// B(cur) after ph1-top drain + end-ph1 bar; A(cur) after ph2-top drain +
// end-ph2 bar. vmcnt per-wave invariant: counted wait BEFORE a barrier.
__device__ __forceinline__ void gload_lds16(const void* g, void* l) {
  __builtin_amdgcn_global_load_lds(
      (const __attribute__((address_space(1))) void*)g,
      (__attribute__((address_space(3))) void*)l, 16, 0, 0);
}

#define SGB() __builtin_amdgcn_sched_barrier(0)
#define VMC(n)  do { SGB(); asm volatile("s_waitcnt vmcnt(" #n ")"); SGB(); } while (0)
#define LGKM(n) do { SGB(); asm volatile("s_waitcnt lgkmcnt(" #n ")"); SGB(); } while (0)
#define BAR() __builtin_amdgcn_s_barrier()
#define DSR64(dst, base, off) \
  asm volatile("ds_read_b64 %0, %1 offset:" off : "=&v"(dst) : "v"(base))

#define FM(RH, R4, CB, KS, AF)                                                 \
  acc[(RH)*4 + (R4)][CB] = __builtin_amdgcn_mfma_f32_16x16x32_fp8_fp8(         \
      AF[R4][KS], bg[CB][KS], acc[(RH)*4 + (R4)][CB], 0, 0, 0)
#define FM4(RH, CB, KS, AF) do {                                               \
  FM(RH, 0, CB, KS, AF); FM(RH, 1, CB, KS, AF);                                \
  FM(RH, 2, CB, KS, AF); FM(RH, 3, CB, KS, AF); } while (0)

__global__ __launch_bounds__(512, 2) void k_gemm(const uint8_t* __restrict__ Aq,
                                                 const uint8_t* __restrict__ Bq,
                                                 float* __restrict__ partial) {
  // [buf][op 0=A 1=B][half][128 rows x 64B] : 64 KiB
  __shared__ uint8_t smq[2][2][2][128 * 64];
  int bid = blockIdx.x;
  int swz = (bid & 7) * 64 + (bid >> 3);     // 512 blocks, 8 XCDs, bijective
  int mt = swz & 31, nt = swz >> 5;
  int tid = threadIdx.x;
  int w = tid >> 6, lane = tid & 63;
  int wm = w >> 2, wn = w & 3;               // 2 x 4 wave grid, 128x64 each
  int lr = lane & 15, lk = lane >> 4;        // row-in-16 / k-granule group
  size_t bm = (size_t)mt * 256, bn = (size_t)nt * 256;
  const uint8_t* Ab = Aq + (bm << 12);
  const uint8_t* Bb = Bq + (bn << 12);

  f32x4 acc[8][4] = {};
  long afE[4][2], afO[4][2], bg[4][2];       // 8B fp8 frags (2 VGPR each)

  // staging: one DMA instr/wave covers 128 rows (16 rows/wave x 8 waves)
  int rowl = lane >> 2;                      // 0..15 within wave's 16 rows
  int swb = ((((lane & 3) << 1) ^ (rowl & 6)) << 3);   // pre-swizzled src col
  auto STAGE_A = [&](int h, int tt, int buf) {
    gload_lds16(Ab + ((size_t)(h * 128 + w * 16 + rowl) << 12) + tt * 64 + swb,
                &smq[buf][0][h][w * 1024]);
  };
  auto STAGE_B = [&](int h, int tt, int buf) {
    gload_lds16(Bb + ((size_t)(h * 128 + w * 16 + rowl) << 12) + tt * 64 + swb,
                &smq[buf][1][h][w * 1024]);
  };

  // ds_read bases (buf0): addr = base + frag*1024 (+4096 for afO)
  uint32_t smb = (uint32_t)(uintptr_t)
      (__attribute__((address_space(3))) uint8_t*)&smq[0][0][0][0];
  uint32_t sx = (uint32_t)(lr & 6);
  uint32_t aA0 = smb + wm * 8192 + lr * 64 + (((uint32_t)lk ^ sx) << 3);
  uint32_t aA1 = smb + wm * 8192 + lr * 64 + (((uint32_t)(4 + lk) ^ sx) << 3);
  uint32_t aB0 = smb + 16384 + (wn >> 1) * 8192 + ((wn & 1) * 64 + lr) * 64 +
                 (((uint32_t)lk ^ sx) << 3);
  uint32_t aB1 = smb + 16384 + (wn >> 1) * 8192 + ((wn & 1) * 64 + lr) * 64 +
                 (((uint32_t)(4 + lk) ^ sx) << 3);

  // prologue: stage t0 (4) + t1 (4); VMC(4)+BAR lands t0 for ALL waves;
  // pre-read afE(t0)+bg01(t0).
  STAGE_A(0, 0, 0); STAGE_A(1, 0, 0);
  STAGE_B(0, 0, 0); STAGE_B(1, 0, 0);
  STAGE_A(0, 1, 1); STAGE_A(1, 1, 1);
  STAGE_B(0, 1, 1); STAGE_B(1, 1, 1);
  VMC(4);
  BAR();
  DSR64(afE[0][0], aA0, "0");    DSR64(afE[0][1], aA1, "0");
  DSR64(afE[1][0], aA0, "1024"); DSR64(afE[1][1], aA1, "1024");
  DSR64(afE[2][0], aA0, "2048"); DSR64(afE[2][1], aA1, "2048");
  DSR64(afE[3][0], aA0, "3072"); DSR64(afE[3][1], aA1, "3072");
  DSR64(bg[0][0], aB0, "0");     DSR64(bg[0][1], aB1, "0");
  DSR64(bg[1][0], aB0, "1024");  DSR64(bg[1][1], aB1, "1024");

  for (int t = 0; t < NT; t++) {
    int t2 = (t + 2 < NT) ? t + 2 : NT - 1;  // clamp keeps vmcnt FIFO uniform
    int cur = t & 1;
    uint32_t bsel = (uint32_t)cur << 15;
    uint32_t A0c = aA0 + bsel, A1c = aA1 + bsel;
    uint32_t B0c = aB0 + bsel, B1c = aB1 + bsel;
    uint32_t A0n = A0c ^ 32768u, A1n = A1c ^ 32768u;
    uint32_t B0n = B0c ^ 32768u, B1n = B1c ^ 32768u;

    // ---- ph0: MM(afE,bg01); mid-reads bg23(cur) ----
    LGKM(0);                       // afE(t)+bg01(t) from ph3-mid(t-1)
    __builtin_amdgcn_s_setprio(1);
    FM4(0, 0, 0, afE);
    SGB();
    DSR64(bg[2][0], B0c, "2048"); DSR64(bg[2][1], B1c, "2048");
    DSR64(bg[3][0], B0c, "3072"); DSR64(bg[3][1], B1c, "3072");
    SGB();
    FM4(0, 1, 0, afE); FM4(0, 0, 1, afE); FM4(0, 1, 1, afE);
    __builtin_amdgcn_s_setprio(0);
    BAR();

    // ---- ph1: MM(afE,bg23); mid-reads afO(cur) ----
    LGKM(0);                       // bg23(t)
    __builtin_amdgcn_s_setprio(1);
    FM4(0, 2, 0, afE);
    SGB();
    DSR64(afO[0][0], A0c, "4096"); DSR64(afO[0][1], A1c, "4096");
    DSR64(afO[1][0], A0c, "5120"); DSR64(afO[1][1], A1c, "5120");
    DSR64(afO[2][0], A0c, "6144"); DSR64(afO[2][1], A1c, "6144");
    DSR64(afO[3][0], A0c, "7168"); DSR64(afO[3][1], A1c, "7168");
    SGB();
    FM4(0, 3, 0, afE); FM4(0, 2, 1, afE); FM4(0, 3, 1, afE);
    __builtin_amdgcn_s_setprio(0);
    BAR();

    // ---- ph2: MM(afO,bg01); stage B(t+2)->cur; VMC(2) ----
    LGKM(0);                       // afO(t)
    __builtin_amdgcn_s_setprio(1);
    FM4(1, 0, 0, afO); FM4(1, 1, 0, afO);
    FM4(1, 0, 1, afO); FM4(1, 1, 1, afO);
    __builtin_amdgcn_s_setprio(0);
    STAGE_B(0, t2, cur); STAGE_B(1, t2, cur);  // B(cur) drained @ph1-top
    VMC(2);                        // drains B(t+1),A(t+1) for THIS wave
    BAR();                         // ...mutual for all waves

    // ---- ph3: MM(afO,bg23); mid-reads afE+bg01(nxt); stage A(t+2) ----
    __builtin_amdgcn_s_setprio(1); // no lgkm: afO/bg23 already waited
    FM4(1, 2, 0, afO);
    SGB();
    DSR64(afE[0][0], A0n, "0");    DSR64(afE[0][1], A1n, "0");
    DSR64(afE[1][0], A0n, "1024"); DSR64(afE[1][1], A1n, "1024");
    DSR64(afE[2][0], A0n, "2048"); DSR64(afE[2][1], A1n, "2048");
    DSR64(afE[3][0], A0n, "3072"); DSR64(afE[3][1], A1n, "3072");
    DSR64(bg[0][0], B0n, "0");     DSR64(bg[0][1], B1n, "0");
    DSR64(bg[1][0], B0n, "1024");  DSR64(bg[1][1], B1n, "1024");
    SGB();
    FM4(1, 3, 0, afO); FM4(1, 2, 1, afO); FM4(1, 3, 1, afO);
    __builtin_amdgcn_s_setprio(0);
    STAGE_A(0, t2, cur); STAGE_A(1, t2, cur);  // A(cur) drained @ph2-top
    BAR();
  }
  VMC(0);
  LGKM(0);   // drain tail DMA + dangling reads before epilogue

  // epilogue: per-row sum of squares over this wave's 64 cols
  // C frag: col = cb*16 + (lane&15), row = rb*16 + (lane>>4)*4 + reg
#pragma unroll
  for (int rb = 0; rb < 8; rb++) {
#pragma unroll
    for (int reg = 0; reg < 4; reg++) {
      float s = 0.f;
#pragma unroll
      for (int cb = 0; cb < 4; cb++) { float v = acc[rb][cb][reg]; s += v * v; }
      s += __shfl_xor(s, 1);
      s += __shfl_xor(s, 2);
      s += __shfl_xor(s, 4);
      s += __shfl_xor(s, 8);
      if (lr == 0) {
        int row = (int)bm + wm * 128 + rb * 16 + lk * 4 + reg;
        partial[(size_t)(nt * 4 + wn) * B_DIM + row] = s;
      }
    }
  }
}

// -------- finish: sum 64 partials, sqrt, undo x64 weight scale ----------
__global__ void k_finish(const float* __restrict__ partial, float* __restrict__ out) {
  int b = blockIdx.x * 256 + threadIdx.x;
  float s = 0.f;
#pragma unroll
  for (int i = 0; i < 64; i++) s += partial[(size_t)i * B_DIM + b];
  out[b] = sqrtf(s) * 0.015625f;
}

extern "C" void kernel_launch(void* const* d_in, const int* in_sizes, int n_in,
                              void* d_out, int out_size, void* d_ws, size_t ws_size,
                              hipStream_t stream) {
  const float* x  = (const float*)d_in[0];
  const float* hw = (const float*)d_in[1];
  float* out = (float*)d_out;
  char* ws = (char*)d_ws;
  uint8_t* xq = (uint8_t*)ws;                                     // 32 MB
  uint8_t* wq = (uint8_t*)(ws + (size_t)B_DIM * K_DIM);           // 16 MB
  float* partial = (float*)(ws + (size_t)B_DIM * K_DIM
                               + (size_t)K_DIM * N_DIM);          // 2 MB
  long long R[3];
  mt_randint3(1367u, R);

  k_prep<<<8192 + 16384, 256, 0, stream>>>(x, xq, hw, wq, R[0], R[1], R[2]);
  k_gemm<<<(B_DIM / 256) * (N_DIM / 256), 512, 0, stream>>>(xq, wq, partial);
  k_finish<<<B_DIM / 256, 256, 0, stream>>>(partial, out);
}

// Round 13
// 227.846 us; speedup vs baseline: 1.4577x; 1.0227x over previous
//
#include <hip/hip_runtime.h>
#include <stdint.h>
#include <math.h>

typedef __bf16 bf16;
typedef float f32x4 __attribute__((ext_vector_type(4)));
typedef long  lx2  __attribute__((ext_vector_type(2)));

#define B_DIM 8192
#define K_DIM 4096
#define N_DIM 4096
#define MEM_H 1048576
#define HMOD  1047552   // MEM_H - 32*32
#define NT    (K_DIM / 64)

// ---------------- host-side numpy legacy RNG replication ----------------
static void mt_randint3(uint32_t seed, long long R[3]) {
  uint32_t mt[624];
  mt[0] = seed;
  for (int i = 1; i < 624; i++)
    mt[i] = 1812433253u * (mt[i - 1] ^ (mt[i - 1] >> 30)) + (uint32_t)i;
  int pos = 624;
  auto next32 = [&]() -> uint32_t {
    if (pos >= 624) {
      for (int i = 0; i < 624; i++) {
        uint32_t y = (mt[i] & 0x80000000u) | (mt[(i + 1) % 624] & 0x7fffffffu);
        uint32_t v = mt[(i + 397) % 624] ^ (y >> 1);
        if (y & 1u) v ^= 0x9908b0dfu;
        mt[i] = v;
      }
      pos = 0;
    }
    uint32_t y = mt[pos++];
    y ^= y >> 11;
    y ^= (y << 7) & 0x9d2c5680u;
    y ^= (y << 15) & 0xefc60000u;
    y ^= y >> 18;
    return y;
  };
  for (int j = 0; j < 3; j++) {
    uint32_t v;
    do { v = next32() & 0x7fffffffu; } while (v > 0x7ffffffdu);
    R[j] = 1LL + (long long)v;
  }
}

// ---------------- f32 -> OCP e4m3fn, RTN-even, with subnormals ----------
__device__ __forceinline__ uint32_t f2e4m3(float f) {
  uint32_t u = __float_as_uint(f);
  uint32_t s = (u >> 24) & 0x80u;
  float a = fabsf(f);
  uint32_t b;
  if (a < 0.015625f) {
    b = (uint32_t)(int)rintf(a * 512.0f);        // 0..8 ; 8 == 2^-6 normal
  } else {
    uint32_t au = __float_as_uint(a);
    au += 0x7FFFFu + ((au >> 20) & 1u);          // round mantissa to 3 bits
    int E = (int)(au >> 23) - 127;
    if (E > 8) b = 0x7Eu;                        // saturate to 448
    else b = (uint32_t)(((E + 7) << 3) | ((au >> 20) & 7u));
  }
  return b | s;
}

// -------- fused pre-pass: quantize x AND build W^T, PACKED layout -------
// Packed 64B k-group: 16B chunk c = [k 8c..8c+7 | k 32+8c..32+8c+7]
// (granule-pair interleave). This makes the GEMM's LDS reads linear.
__global__ void k_prep(const float* __restrict__ x, uint8_t* __restrict__ xq,
                       const float* __restrict__ hw, uint8_t* __restrict__ wq,
                       long long R1, long long R2, long long R3) {
  if (blockIdx.x < 8192) {
    int id = blockIdx.x * 256 + threadIdx.x;     // one packed 16B chunk
    int row = id >> 8, q = id & 255;
    int g = q >> 2, c = q & 3;
    const float* base = x + (size_t)row * 4096 + g * 64 + c * 8;
    f32x4 v0 = *(const f32x4*)(base);
    f32x4 v1 = *(const f32x4*)(base + 4);
    f32x4 v2 = *(const f32x4*)(base + 32);
    f32x4 v3 = *(const f32x4*)(base + 36);
    uint32_t r0 = f2e4m3(v0[0]) | (f2e4m3(v0[1]) << 8) |
                  (f2e4m3(v0[2]) << 16) | (f2e4m3(v0[3]) << 24);
    uint32_t r1 = f2e4m3(v1[0]) | (f2e4m3(v1[1]) << 8) |
                  (f2e4m3(v1[2]) << 16) | (f2e4m3(v1[3]) << 24);
    uint32_t r2 = f2e4m3(v2[0]) | (f2e4m3(v2[1]) << 8) |
                  (f2e4m3(v2[2]) << 16) | (f2e4m3(v2[3]) << 24);
    uint32_t r3 = f2e4m3(v3[0]) | (f2e4m3(v3[1]) << 8) |
                  (f2e4m3(v3[2]) << 16) | (f2e4m3(v3[3]) << 24);
    ((uint4*)xq)[id] = make_uint4(r0, r1, r2, r3);
  } else {
    int tile = blockIdx.x - 8192;
    int kb = tile & 127, nb = tile >> 7;
    long long v = (long long)kb * R3 + (long long)nb * R2 + R1;
    int start = (int)((v % 2147483647LL) % (long long)HMOD);
    const float* src = hw + start;
    int t = threadIdx.x;
    int nl = t >> 3, k4 = t & 7;                 // 4 bytes j=k4*4.. of tile kb
    uint32_t b = 0;
#pragma unroll
    for (int j = 0; j < 4; j++)
      b |= f2e4m3(src[(k4 * 4 + j) * 32 + nl] * 64.0f) << (8 * j);
    // packed dst: group kb>>1, chunk k4>>1, half kb&1, sub (k4&1)*4
    size_t off = (size_t)(nb * 32 + nl) * 4096 + (kb >> 1) * 64 +
                 (k4 >> 1) * 16 + (kb & 1) * 8 + (k4 & 1) * 4;
    *(uint32_t*)(wq + off) = b;
  }
}

// ---- 256x256x64 fp8 GEMM: packed-linear LDS (zero-conflict reads) ------
// LDS 64KB. Unit = 16 rows x 64B = 1KB, chunk-major (slot = chunk*16+row =
// DMA lane order). Every fragment read = ds_read_b128 at base+lane*16,
// dense over the unit -> conflict-free by construction; each b128 holds
// both k-slices ([0]=ks0, [1]=ks1). Ledger identical to R12: 4 DMA/tile,
// prologue VMC(4), VMC(2) @ph2; vmcnt per-wave => counted wait BEFORE BAR.
__device__ __forceinline__ void gload_lds16(const void* g, void* l) {
  __builtin_amdgcn_global_load_lds(
      (const __attribute__((address_space(1))) void*)g,
      (__attribute__((address_space(3))) void*)l, 16, 0, 0);
}

#define SGB() __builtin_amdgcn_sched_barrier(0)
#define VMC(n)  do { SGB(); asm volatile("s_waitcnt vmcnt(" #n ")"); SGB(); } while (0)
#define LGKM(n) do { SGB(); asm volatile("s_waitcnt lgkmcnt(" #n ")"); SGB(); } while (0)
#define BAR() __builtin_amdgcn_s_barrier()
#define DSR128(dst, base, off) \
  asm volatile("ds_read_b128 %0, %1 offset:" off : "=&v"(dst) : "v"(base))

#define FM(RH, R4, CB, KS, AF)                                                 \
  acc[(RH)*4 + (R4)][CB] = __builtin_amdgcn_mfma_f32_16x16x32_fp8_fp8(         \
      AF[R4][KS], bg[CB][KS], acc[(RH)*4 + (R4)][CB], 0, 0, 0)
#define FM4(RH, CB, KS, AF) do {                                               \
  FM(RH, 0, CB, KS, AF); FM(RH, 1, CB, KS, AF);                                \
  FM(RH, 2, CB, KS, AF); FM(RH, 3, CB, KS, AF); } while (0)

__global__ __launch_bounds__(512, 2) void k_gemm(const uint8_t* __restrict__ Aq,
                                                 const uint8_t* __restrict__ Bq,
                                                 float* __restrict__ partial) {
  // [buf][op 0=A 1=B][half][8 units x 1KB] : 64 KiB
  __shared__ uint8_t smq[2][2][2][128 * 64];
  int bid = blockIdx.x;
  int swz = (bid & 7) * 64 + (bid >> 3);     // 512 blocks, 8 XCDs, bijective
  int mt = swz & 31, nt = swz >> 5;
  int tid = threadIdx.x;
  int w = tid >> 6, lane = tid & 63;
  int wm = w >> 2, wn = w & 3;               // 2 x 4 wave grid, 128x64 each
  int lr = lane & 15, lk = lane >> 4;
  size_t bm = (size_t)mt * 256, bn = (size_t)nt * 256;
  const uint8_t* Ab = Aq + (bm << 12);
  const uint8_t* Bb = Bq + (bn << 12);

  f32x4 acc[8][4] = {};
  lx2 afE[4], afO[4], bg[4];                 // [unit]; [0]=ks0, [1]=ks1

  // staging: 1 DMA/wave covers one 16-row unit; lane l fetches
  // (row = l&15, chunk = l>>4) -> LDS slot l (chunk-major layout).
  auto STAGE_A = [&](int h, int tt, int buf) {
    gload_lds16(Ab + ((size_t)(h * 128 + w * 16 + lr) << 12) + tt * 64 + lk * 16,
                &smq[buf][0][h][w * 1024]);
  };
  auto STAGE_B = [&](int h, int tt, int buf) {
    gload_lds16(Bb + ((size_t)(h * 128 + w * 16 + lr) << 12) + tt * 64 + lk * 16,
                &smq[buf][1][h][w * 1024]);
  };

  // read bases (buf0): perfectly linear base + lane*16
  uint32_t smb = (uint32_t)(uintptr_t)
      (__attribute__((address_space(3))) uint8_t*)&smq[0][0][0][0];
  uint32_t aA = smb + wm * 8192 + lane * 16;
  uint32_t aB = smb + 16384 + (wn >> 1) * 8192 + (wn & 1) * 4096 + lane * 16;

  // prologue: stage t0 (4 DMA) + t1 (4); VMC(4)+BAR lands t0 for ALL waves;
  // pre-read afE(t0) + bg01(t0).
  STAGE_A(0, 0, 0); STAGE_A(1, 0, 0);
  STAGE_B(0, 0, 0); STAGE_B(1, 0, 0);
  STAGE_A(0, 1, 1); STAGE_A(1, 1, 1);
  STAGE_B(0, 1, 1); STAGE_B(1, 1, 1);
  VMC(4);
  BAR();
  DSR128(afE[0], aA, "0");    DSR128(afE[1], aA, "1024");
  DSR128(afE[2], aA, "2048"); DSR128(afE[3], aA, "3072");
  DSR128(bg[0], aB, "0");     DSR128(bg[1], aB, "1024");

  for (int t = 0; t < NT; t++) {
    int t2 = (t + 2 < NT) ? t + 2 : NT - 1;  // clamp keeps vmcnt FIFO uniform
    int cur = t & 1;
    uint32_t bsel = (uint32_t)cur << 15;
    uint32_t Ac = aA + bsel, Bc = aB + bsel;
    uint32_t An = Ac ^ 32768u, Bn = Bc ^ 32768u;

    // ---- ph0: MM(afE,bg01); mid-reads bg23(cur) ----
    LGKM(0);                       // afE(t)+bg01(t) from ph3-mid(t-1)
    __builtin_amdgcn_s_setprio(1);
    FM4(0, 0, 0, afE);
    SGB();
    DSR128(bg[2], Bc, "2048"); DSR128(bg[3], Bc, "3072");
    SGB();
    FM4(0, 1, 0, afE); FM4(0, 0, 1, afE); FM4(0, 1, 1, afE);
    __builtin_amdgcn_s_setprio(0);
    BAR();

    // ---- ph1: MM(afE,bg23); mid-reads afO(cur) ----
    LGKM(0);                       // bg23(t)
    __builtin_amdgcn_s_setprio(1);
    FM4(0, 2, 0, afE);
    SGB();
    DSR128(afO[0], Ac, "4096"); DSR128(afO[1], Ac, "5120");
    DSR128(afO[2], Ac, "6144"); DSR128(afO[3], Ac, "7168");
    SGB();
    FM4(0, 3, 0, afE); FM4(0, 2, 1, afE); FM4(0, 3, 1, afE);
    __builtin_amdgcn_s_setprio(0);
    BAR();

    // ---- ph2: MM(afO,bg01); stage B(t+2)->cur; VMC(2) ----
    LGKM(0);                       // afO(t)
    __builtin_amdgcn_s_setprio(1);
    FM4(1, 0, 0, afO); FM4(1, 1, 0, afO);
    FM4(1, 0, 1, afO); FM4(1, 1, 1, afO);
    __builtin_amdgcn_s_setprio(0);
    STAGE_B(0, t2, cur); STAGE_B(1, t2, cur);  // cur-B reads done by end-ph1
    VMC(2);                        // drains B(t+1),A(t+1) for THIS wave
    BAR();                         // ...mutual for all waves

    // ---- ph3: MM(afO,bg23); mid-reads afE+bg01(nxt); stage A(t+2) ----
    __builtin_amdgcn_s_setprio(1); // no lgkm: afO/bg23 already waited
    FM4(1, 2, 0, afO);
    SGB();
    DSR128(afE[0], An, "0");    DSR128(afE[1], An, "1024");
    DSR128(afE[2], An, "2048"); DSR128(afE[3], An, "3072");
    DSR128(bg[0], Bn, "0");     DSR128(bg[1], Bn, "1024");
    SGB();
    FM4(1, 3, 0, afO); FM4(1, 2, 1, afO); FM4(1, 3, 1, afO);
    __builtin_amdgcn_s_setprio(0);
    STAGE_A(0, t2, cur); STAGE_A(1, t2, cur);  // cur-A reads done by end-ph2
    BAR();
  }
  VMC(0);
  LGKM(0);   // drain tail DMA + dangling reads before epilogue

  // epilogue: per-row sum of squares over this wave's 64 cols
  // C frag: col = cb*16 + (lane&15), row = rb*16 + (lane>>4)*4 + reg
#pragma unroll
  for (int rb = 0; rb < 8; rb++) {
#pragma unroll
    for (int reg = 0; reg < 4; reg++) {
      float s = 0.f;
#pragma unroll
      for (int cb = 0; cb < 4; cb++) { float v = acc[rb][cb][reg]; s += v * v; }
      s += __shfl_xor(s, 1);
      s += __shfl_xor(s, 2);
      s += __shfl_xor(s, 4);
      s += __shfl_xor(s, 8);
      if (lr == 0) {
        int row = (int)bm + wm * 128 + rb * 16 + lk * 4 + reg;
        partial[(size_t)(nt * 4 + wn) * B_DIM + row] = s;
      }
    }
  }
}

// -------- finish: sum 64 partials, sqrt, undo x64 weight scale ----------
__global__ void k_finish(const float* __restrict__ partial, float* __restrict__ out) {
  int b = blockIdx.x * 256 + threadIdx.x;
  float s = 0.f;
#pragma unroll
  for (int i = 0; i < 64; i++) s += partial[(size_t)i * B_DIM + b];
  out[b] = sqrtf(s) * 0.015625f;
}

extern "C" void kernel_launch(void* const* d_in, const int* in_sizes, int n_in,
                              void* d_out, int out_size, void* d_ws, size_t ws_size,
                              hipStream_t stream) {
  const float* x  = (const float*)d_in[0];
  const float* hw = (const float*)d_in[1];
  float* out = (float*)d_out;
  char* ws = (char*)d_ws;
  uint8_t* xq = (uint8_t*)ws;                                     // 32 MB
  uint8_t* wq = (uint8_t*)(ws + (size_t)B_DIM * K_DIM);           // 16 MB
  float* partial = (float*)(ws + (size_t)B_DIM * K_DIM
                               + (size_t)K_DIM * N_DIM);          // 2 MB
  long long R[3];
  mt_randint3(1367u, R);

  k_prep<<<8192 + 16384, 256, 0, stream>>>(x, xq, hw, wq, R[0], R[1], R[2]);
  k_gemm<<<(B_DIM / 256) * (N_DIM / 256), 512, 0, stream>>>(xq, wq, partial);
  k_finish<<<B_DIM / 256, 256, 0, stream>>>(partial, out);
}